// Round 4
// baseline (1407.964 us; speedup 1.0000x reference)
//
#include <hip/hip_runtime.h>
#include <hip/hip_bf16.h>
#include <math.h>

// B=1, S=512, N=384, D=64, H=32, DP=128, DQK=64
// ws layout (float offsets)
#define WS_X        0u          // x f32 [196608][64]                 = 12582912
#define WS_AEXT     12582912u   // AH frag bf16 [768*16][64][8] = 3145728 f, then AL same
#define WS_BEXT     18874368u   // BH, BL same
#define WS_QN       25165824u   // [2][384][64]
#define WS_SW       25214976u   // [2][512]
#define WS_WSQ      25216000u   // [512]
#define WS_BPP      25216512u   // [256]
#define WS_WPF      25216768u   // WpF bf16 frag-layout [2][16][32][64][8] = 262144 f
#define WS_BIG      25478912u   // kraw half [98304][128] f32 = 12582912 f

typedef __attribute__((ext_vector_type(8))) short bf16x8;
typedef __attribute__((ext_vector_type(4))) float f32x4;

union U4B8 { uint4 u4; unsigned u[4]; bf16x8 v; };

__device__ __forceinline__ unsigned short f2b(float x) {
    __hip_bfloat16 b = __float2bfloat16(x);
    return *reinterpret_cast<unsigned short*>(&b);
}
__device__ __forceinline__ float b2f(unsigned short u) {
    __hip_bfloat16 b = *reinterpret_cast<__hip_bfloat16*>(&u);
    return __bfloat162float(b);
}

#define GLDS(g, l) __builtin_amdgcn_global_load_lds(                                   \
    (const __attribute__((address_space(1))) unsigned int*)(g),                        \
    (__attribute__((address_space(3))) unsigned int*)(l), 16, 0, 0)

// ---------------- K1: LayerNorm over D=64, one wave per row ----------------
__global__ __launch_bounds__(256) void k1_ln(const float* __restrict__ msa,
                                             const float* __restrict__ g,
                                             const float* __restrict__ bb,
                                             float* __restrict__ x) {
    int row  = blockIdx.x * 4 + (threadIdx.x >> 6);
    int lane = threadIdx.x & 63;
    float v = msa[(size_t)row * 64 + lane];
    float sum = v;
    #pragma unroll
    for (int m = 1; m < 64; m <<= 1) sum += __shfl_xor(sum, m);
    float mean = sum * (1.0f / 64.0f);
    float dv = v - mean;
    float sq = dv * dv;
    #pragma unroll
    for (int m = 1; m < 64; m <<= 1) sq += __shfl_xor(sq, m);
    float r = rsqrtf(sq * (1.0f / 64.0f) + 1e-5f);
    x[(size_t)row * 64 + lane] = dv * r * g[lane] + bb[lane];
}

// ---------------- K2: q projection (s=0 rows) + LN ----------------
__global__ __launch_bounds__(128) void k2_q(const float* __restrict__ x,
                                            const float* __restrict__ Wq,
                                            const float* __restrict__ qg,
                                            const float* __restrict__ qb,
                                            float* __restrict__ qn) {
    int n = blockIdx.x;
    int t = threadIdx.x >> 6;
    int d = threadIdx.x & 63;
    const float* xr = x + (size_t)n * 64;
    const float* w  = Wq + (size_t)(t * 64 + d) * 64;
    float acc = 0.f;
    #pragma unroll 8
    for (int dd = 0; dd < 64; ++dd) acc += xr[dd] * w[dd];
    float sum = acc;
    #pragma unroll
    for (int m = 1; m < 64; m <<= 1) sum += __shfl_xor(sum, m);
    float mean = sum * (1.0f / 64.0f);
    float dv = acc - mean;
    float sq = dv * dv;
    #pragma unroll
    for (int m = 1; m < 64; m <<= 1) sq += __shfl_xor(sq, m);
    float r = rsqrtf(sq * (1.0f / 64.0f) + 1e-5f);
    qn[(size_t)(t * 384 + n) * 64 + d] = dv * r * qg[d] + qb[d];
}

// ---------------- fp32 NT GEMM (K3a only: x @ Wk^T) ----------------
__global__ __launch_bounds__(256) void gemm_nt(const float* __restrict__ A,
                                               const float* __restrict__ Bm,
                                               float* __restrict__ C,
                                               int K, int lda, int ldb, int ldc) {
    __shared__ float AsT[32][132];
    __shared__ float BsT[32][132];
    int t  = threadIdx.x;
    int m0 = blockIdx.x * 128, n0 = blockIdx.y * 128;
    int tr = t >> 4, tc = t & 15;
    float acc[8][8] = {};
    int rrow = t >> 3;
    int kk   = (t & 7) * 4;
    for (int k0 = 0; k0 < K; k0 += 32) {
        #pragma unroll
        for (int l = 0; l < 4; ++l) {
            int row = rrow + 32 * l;
            float4 va = *(const float4*)(A + (size_t)(m0 + row) * lda + k0 + kk);
            AsT[kk + 0][row] = va.x; AsT[kk + 1][row] = va.y;
            AsT[kk + 2][row] = va.z; AsT[kk + 3][row] = va.w;
            float4 vb = *(const float4*)(Bm + (size_t)(n0 + row) * ldb + k0 + kk);
            BsT[kk + 0][row] = vb.x; BsT[kk + 1][row] = vb.y;
            BsT[kk + 2][row] = vb.z; BsT[kk + 3][row] = vb.w;
        }
        __syncthreads();
        #pragma unroll 4
        for (int k = 0; k < 32; ++k) {
            float a[8], b[8];
            *(float4*)&a[0] = *(const float4*)&AsT[k][tr * 8];
            *(float4*)&a[4] = *(const float4*)&AsT[k][tr * 8 + 4];
            *(float4*)&b[0] = *(const float4*)&BsT[k][tc * 8];
            *(float4*)&b[4] = *(const float4*)&BsT[k][tc * 8 + 4];
            #pragma unroll
            for (int q = 0; q < 8; ++q)
                #pragma unroll
                for (int j = 0; j < 8; ++j)
                    acc[q][j] += a[q] * b[j];
        }
        __syncthreads();
    }
    #pragma unroll
    for (int q = 0; q < 8; ++q) {
        float* cp = C + (size_t)(m0 + tr * 8 + q) * ldc + n0 + tc * 8;
        *(float4*)cp       = make_float4(acc[q][0], acc[q][1], acc[q][2], acc[q][3]);
        *(float4*)(cp + 4) = make_float4(acc[q][4], acc[q][5], acc[q][6], acc[q][7]);
    }
}

// ---------------- K3b: k LN + dot with qn, reduce over n -> sw[2][512] ----------------
__global__ __launch_bounds__(256) void k3b_sw(const float* __restrict__ kraw,
                                              const float* __restrict__ qn,
                                              const float* __restrict__ kg,
                                              const float* __restrict__ kb,
                                              float* __restrict__ sw, int sc) {
    int sl   = blockIdx.x;
    int s    = sc * 256 + sl;
    int w    = threadIdx.x >> 6;
    int lane = threadIdx.x & 63;
    float gv = kg[lane], bv = kb[lane];
    float acc0 = 0.f, acc1 = 0.f;
    for (int n = w; n < 384; n += 4) {
        const float* row = kraw + ((size_t)sl * 384 + n) * 128;
        #pragma unroll
        for (int tt = 0; tt < 2; ++tt) {
            float v = row[tt * 64 + lane];
            float sum = v;
            #pragma unroll
            for (int m = 1; m < 64; m <<= 1) sum += __shfl_xor(sum, m);
            float mean = sum * (1.0f / 64.0f);
            float dv = v - mean;
            float sq = dv * dv;
            #pragma unroll
            for (int m = 1; m < 64; m <<= 1) sq += __shfl_xor(sq, m);
            float r  = rsqrtf(sq * (1.0f / 64.0f) + 1e-5f);
            float kn = dv * r * gv + bv;
            float p  = kn * qn[(size_t)(tt * 384 + n) * 64 + lane];
            #pragma unroll
            for (int m = 1; m < 64; m <<= 1) p += __shfl_xor(p, m);
            if (tt == 0) acc0 += p; else acc1 += p;
        }
    }
    __shared__ float red[8];
    if (lane == 0) { red[w] = acc0; red[4 + w] = acc1; }
    __syncthreads();
    if (threadIdx.x == 0) {
        float t0 = red[0] + red[1] + red[2] + red[3];
        float t1 = red[4] + red[5] + red[6] + red[7];
        sw[s]       = t0 * 0.125f / 384.0f;
        sw[512 + s] = t1 * 0.125f / 384.0f;
    }
}

// ---------------- K4: lambda, softmax over s, sqrt weights ----------------
__global__ __launch_bounds__(512) void k4_softmax(const float* __restrict__ sw,
                                                  const float* __restrict__ lq1,
                                                  const float* __restrict__ lk1,
                                                  const float* __restrict__ lq2,
                                                  const float* __restrict__ lk2,
                                                  float* __restrict__ wsq) {
    int s = threadIdx.x;
    float l1 = 0.f, l2 = 0.f;
    for (int i = 0; i < 64; ++i) { l1 += lq1[i] * lk1[i]; l2 += lq2[i] * lk2[i]; }
    float lam = expf(l1) - expf(l2) + 1.0f;
    float v = sw[s] - lam * sw[512 + s];
    __shared__ float red[512];
    red[s] = v;
    __syncthreads();
    for (int off = 256; off > 0; off >>= 1) {
        if (s < off) red[s] = fmaxf(red[s], red[s + off]);
        __syncthreads();
    }
    float mx = red[0];
    __syncthreads();
    float e = expf(v - mx);
    red[s] = e;
    __syncthreads();
    for (int off = 256; off > 0; off >>= 1) {
        if (s < off) red[s] += red[s + off];
        __syncthreads();
    }
    wsq[s] = sqrtf(e / red[0] + 1e-32f);
}

// ---------------- K5: build A/B hi-lo splits in MFMA-frag-native layout ----------------
// Frag layout: array[(panel*16 + kstep)*64 + slot][8] where panel = m>>4,
// kstep = s>>5, slot = (m&15) | (((s>>3)&3)<<4), element = s&7.
__global__ __launch_bounds__(256) void k5_ab(const float* __restrict__ x,
                                             const float* __restrict__ Wl,
                                             const float* __restrict__ Wr,
                                             const float* __restrict__ wsq,
                                             unsigned short* __restrict__ AHo,
                                             unsigned short* __restrict__ ALo,
                                             unsigned short* __restrict__ BHo,
                                             unsigned short* __restrict__ BLo) {
    int i  = blockIdx.x;
    int s0 = blockIdx.y * 64;
    int t  = threadIdx.x;
    __shared__ __align__(16) float wl[2048], wr[2048];
    __shared__ float xT[64][69];
    ((float4*)wl)[t * 2]     = ((const float4*)Wl)[t * 2];
    ((float4*)wl)[t * 2 + 1] = ((const float4*)Wl)[t * 2 + 1];
    ((float4*)wr)[t * 2]     = ((const float4*)Wr)[t * 2];
    ((float4*)wr)[t * 2 + 1] = ((const float4*)Wr)[t * 2 + 1];
    {
        int s_l = t >> 2, d0 = (t & 3) * 16;
        const float* xr = x + ((size_t)(s0 + s_l) * 384 + i) * 64 + d0;
        #pragma unroll
        for (int j = 0; j < 4; ++j) {
            float4 v = *(const float4*)(xr + j * 4);
            xT[d0 + j * 4 + 0][s_l] = v.x; xT[d0 + j * 4 + 1][s_l] = v.y;
            xT[d0 + j * 4 + 2][s_l] = v.z; xT[d0 + j * 4 + 3][s_l] = v.w;
        }
    }
    __syncthreads();
    int c = t >> 3, so = (t & 7) * 8;
    float aa[8] = {}, bb2[8] = {};
    #pragma unroll 8
    for (int d = 0; d < 64; ++d) {
        float wlv = wl[c * 64 + d], wrv = wr[c * 64 + d];
        #pragma unroll
        for (int q = 0; q < 8; ++q) {
            float xv = xT[d][so + q];
            aa[q]  += xv * wlv;
            bb2[q] += xv * wrv;
        }
    }
    #pragma unroll
    for (int q = 0; q < 8; ++q) {
        float wq = wsq[s0 + so + q];
        aa[q] *= wq; bb2[q] *= wq;
    }
    int m = i * 32 + c;
    int s = s0 + so;
    size_t idx = (((size_t)(m >> 4) * 16 + (s >> 5)) * 64 + ((m & 15) | (((s >> 3) & 3) << 4))) * 8;
    {
        unsigned short h[8], l[8];
        #pragma unroll
        for (int q = 0; q < 8; ++q) { h[q] = f2b(aa[q]); l[q] = f2b(aa[q] - b2f(h[q])); }
        *(uint4*)&AHo[idx] = make_uint4((unsigned)h[0] | ((unsigned)h[1] << 16), (unsigned)h[2] | ((unsigned)h[3] << 16),
                                        (unsigned)h[4] | ((unsigned)h[5] << 16), (unsigned)h[6] | ((unsigned)h[7] << 16));
        *(uint4*)&ALo[idx] = make_uint4((unsigned)l[0] | ((unsigned)l[1] << 16), (unsigned)l[2] | ((unsigned)l[3] << 16),
                                        (unsigned)l[4] | ((unsigned)l[5] << 16), (unsigned)l[6] | ((unsigned)l[7] << 16));
    }
    {
        unsigned short h[8], l[8];
        #pragma unroll
        for (int q = 0; q < 8; ++q) { h[q] = f2b(bb2[q]); l[q] = f2b(bb2[q] - b2f(h[q])); }
        *(uint4*)&BHo[idx] = make_uint4((unsigned)h[0] | ((unsigned)h[1] << 16), (unsigned)h[2] | ((unsigned)h[3] << 16),
                                        (unsigned)h[4] | ((unsigned)h[5] << 16), (unsigned)h[6] | ((unsigned)h[7] << 16));
        *(uint4*)&BLo[idx] = make_uint4((unsigned)l[0] | ((unsigned)l[1] << 16), (unsigned)l[2] | ((unsigned)l[3] << 16),
                                        (unsigned)l[4] | ((unsigned)l[5] << 16), (unsigned)l[6] | ((unsigned)l[7] << 16));
    }
}

// ---------------- prep: WpF frag layout [bsel][nb][kstep][lane][8] + bpP ----------------
__global__ __launch_bounds__(256) void prep_wp(const float* __restrict__ Wp,
                                               const float* __restrict__ bp,
                                               unsigned short* __restrict__ WpF,
                                               float* __restrict__ bpP) {
    int gid = blockIdx.x * 256 + threadIdx.x;      // 256 blocks -> 65536 groups
    int lane  = gid & 63;
    int kstep = (gid >> 6) & 31;
    int nb    = (gid >> 11) & 15;
    int bsel  = gid >> 15;
    int rl = lane & 15, kg = lane >> 4;
    int urow = nb * 16 + rl;
    int srow = (urow & 1) ? 128 + (urow >> 1) : (urow >> 1);
    int k0 = kstep * 32 + kg * 8;
    const float* src = Wp + (size_t)srow * 1024 + k0;
    unsigned short o[8];
    #pragma unroll
    for (int e = 0; e < 8; ++e) {
        float w = src[e];
        unsigned short h = f2b(w);
        o[e] = bsel ? f2b(w - b2f(h)) : h;
    }
    *(uint4*)&WpF[(size_t)gid * 8] = make_uint4(
        (unsigned)o[0] | ((unsigned)o[1] << 16), (unsigned)o[2] | ((unsigned)o[3] << 16),
        (unsigned)o[4] | ((unsigned)o[5] << 16), (unsigned)o[6] | ((unsigned)o[7] << 16));
    if (blockIdx.x == 0) {
        int tt = threadIdx.x;
        bpP[tt] = bp[(tt & 1) ? 128 + (tt >> 1) : (tt >> 1)];
    }
}

// ---------------- FUSED: outer tile (shared-staged bf16x3) + Wp projection + SwiGLU ----------------
// 1D grid 9216, XCD-chunked: each XCD gets a contiguous by-range, bx fastest.
__global__ __launch_bounds__(256) void gemm_fused(const unsigned short* __restrict__ AH,
                                                  const unsigned short* __restrict__ AL,
                                                  const unsigned short* __restrict__ BHm,
                                                  const unsigned short* __restrict__ BLm,
                                                  const unsigned short* __restrict__ WpF,
                                                  const float* __restrict__ bpP,
                                                  float* __restrict__ out) {
    __shared__ __align__(16) unsigned char smem[65792];   // staging 64KB aliased with pa 65792B
    unsigned* pa = (unsigned*)smem;                       // [16][1028] packed hi|lo u32 (padded rows)

    const int t = threadIdx.x;
    const int wave = t >> 6, lane = t & 63;
    const int id = blockIdx.x;
    const int xcd = id & 7;
    const int lin = xcd * 1152 + (id >> 3);
    const int by = lin / 96, bx = lin - by * 96;
    const int m0 = bx * 128, n0 = by * 128;
    const int wm = (wave & 1) * 64, wn = (wave >> 1) * 64;
    const int kgrp = lane >> 4, rl = lane & 15;
    f32x4 acc[4][4] = {};

    // wave w stages array w: 0->AH, 1->AL, 2->BH, 3->BL
    const unsigned short* srcArr = (wave == 0) ? AH : (wave == 1) ? AL : (wave == 2) ? BHm : BLm;
    const int pbase = ((wave < 2) ? m0 : n0) >> 4;
    unsigned short* dstBase = (unsigned short*)(smem + wave * 16384);

    for (int k0 = 0; k0 < 512; k0 += 64) {
        const int kt = k0 >> 5;
        #pragma unroll
        for (int fi = 0; fi < 16; ++fi) {
            const int pane = fi >> 1, kk = fi & 1;
            GLDS(srcArr + (((size_t)(pbase + pane) * 16 + kt + kk) * 64) * 8 + lane * 8,
                 dstBase + fi * 512);
        }
        __syncthreads();
        #pragma unroll
        for (int kk = 0; kk < 2; ++kk) {
            bf16x8 aHf[4], aLf[4], bHf[4], bLf[4];
            #pragma unroll
            for (int f = 0; f < 4; ++f) {
                const int fiA = (((wm >> 4) + f) * 2 + kk) * 1024;
                aHf[f] = *(const bf16x8*)(smem + fiA + lane * 16);
                aLf[f] = *(const bf16x8*)(smem + 16384 + fiA + lane * 16);
                const int fiB = (((wn >> 4) + f) * 2 + kk) * 1024;
                bHf[f] = *(const bf16x8*)(smem + 32768 + fiB + lane * 16);
                bLf[f] = *(const bf16x8*)(smem + 49152 + fiB + lane * 16);
            }
            #pragma unroll
            for (int mf = 0; mf < 4; ++mf)
                #pragma unroll
                for (int nf = 0; nf < 4; ++nf) {
                    acc[mf][nf] = __builtin_amdgcn_mfma_f32_16x16x32_bf16(aHf[mf], bHf[nf], acc[mf][nf], 0, 0, 0);
                    acc[mf][nf] = __builtin_amdgcn_mfma_f32_16x16x32_bf16(aLf[mf], bHf[nf], acc[mf][nf], 0, 0, 0);
                    acc[mf][nf] = __builtin_amdgcn_mfma_f32_16x16x32_bf16(aHf[mf], bLf[nf], acc[mf][nf], 0, 0, 0);
                }
        }
        __syncthreads();
    }

    // ---- spill outer tile to pa as packed hi|lo bf16 (padded rows: 2-way reads) ----
    #pragma unroll
    for (int mf = 0; mf < 4; ++mf) {
        #pragma unroll
        for (int nf = 0; nf < 4; ++nf) {
            #pragma unroll
            for (int r = 0; r < 4; ++r) {
                int mloc = wm + mf * 16 + kgrp * 4 + r;
                int nloc = wn + nf * 16 + rl;
                int p = ((mloc >> 5) << 2) | (nloc >> 5);
                int k = ((mloc & 31) << 5) | (nloc & 31);
                float v = acc[mf][nf][r];
                unsigned short h = f2b(v);
                unsigned short l = f2b(v - b2f(h));
                pa[p * 1028 + k] = (unsigned)h | ((unsigned)l << 16);
            }
        }
    }
    __syncthreads();

    // ---- epilogue GEMM: [16 pairs] x WpF^T, single pass over all 3 sections ----
    f32x4 acc2[4] = {};
    const unsigned* paRow = pa + rl * 1028 + kgrp * 8;
    #pragma unroll 4
    for (int ks = 0; ks < 32; ++ks) {
        U4B8 ua0, ua1, aHf, aLf;
        ua0.u4 = *(const uint4*)(paRow + ks * 32);
        ua1.u4 = *(const uint4*)(paRow + ks * 32 + 4);
        aHf.u[0] = (ua0.u[0] & 0xffffu) | (ua0.u[1] << 16);
        aHf.u[1] = (ua0.u[2] & 0xffffu) | (ua0.u[3] << 16);
        aHf.u[2] = (ua1.u[0] & 0xffffu) | (ua1.u[1] << 16);
        aHf.u[3] = (ua1.u[2] & 0xffffu) | (ua1.u[3] << 16);
        aLf.u[0] = (ua0.u[0] >> 16) | (ua0.u[1] & 0xffff0000u);
        aLf.u[1] = (ua0.u[2] >> 16) | (ua0.u[3] & 0xffff0000u);
        aLf.u[2] = (ua1.u[0] >> 16) | (ua1.u[1] & 0xffff0000u);
        aLf.u[3] = (ua1.u[2] >> 16) | (ua1.u[3] & 0xffff0000u);
        bf16x8 bHf[4], bLf[4];
        #pragma unroll
        for (int nf = 0; nf < 4; ++nf) {
            const int nb = wave * 4 + nf;
            bHf[nf] = *(const bf16x8*)&WpF[(size_t)((nb * 32 + ks) * 64 + lane) * 8];
            bLf[nf] = *(const bf16x8*)&WpF[(size_t)(((16 + nb) * 32 + ks) * 64 + lane) * 8];
        }
        #pragma unroll
        for (int nf = 0; nf < 4; ++nf) {
            acc2[nf] = __builtin_amdgcn_mfma_f32_16x16x32_bf16(aHf.v, bHf[nf], acc2[nf], 0, 0, 0);
            acc2[nf] = __builtin_amdgcn_mfma_f32_16x16x32_bf16(aLf.v, bHf[nf], acc2[nf], 0, 0, 0);
            acc2[nf] = __builtin_amdgcn_mfma_f32_16x16x32_bf16(aHf.v, bLf[nf], acc2[nf], 0, 0, 0);
        }
    }

    // ---- bias + SwiGLU + store ----
    const int parity = rl & 1;
    #pragma unroll
    for (int nf = 0; nf < 4; ++nf) {
        const int np = wave * 64 + nf * 16 + rl;   // logical u-row (interleaved val/gate)
        const float bias = bpP[np];
        const int ocol = np >> 1;
        #pragma unroll
        for (int r = 0; r < 4; ++r) {
            float own = acc2[nf][r] + bias;
            float oth = __shfl_xor(own, 1);
            float v = parity ? oth : own;
            float g = parity ? own : oth;
            float res = v * (g / (1.0f + expf(-g)));
            if (parity == (r >> 1)) {
                int p = kgrp * 4 + r;               // pair index = C row
                int i = bx * 4 + (p >> 2);
                int j = by * 4 + (p & 3);
                out[((size_t)i * 384 + j) * 128 + ocol] = res;
            }
        }
    }
}

extern "C" void kernel_launch(void* const* d_in, const int* in_sizes, int n_in,
                              void* d_out, int out_size, void* d_ws, size_t ws_size,
                              hipStream_t stream) {
    const float* msa  = (const float*)d_in[0];
    const float* ln_g = (const float*)d_in[1];
    const float* ln_b = (const float*)d_in[2];
    const float* Wq   = (const float*)d_in[3];
    const float* Wk   = (const float*)d_in[4];
    const float* qn_g = (const float*)d_in[5];
    const float* qn_b = (const float*)d_in[6];
    const float* kn_g = (const float*)d_in[7];
    const float* kn_b = (const float*)d_in[8];
    const float* lq1  = (const float*)d_in[9];
    const float* lk1  = (const float*)d_in[10];
    const float* lq2  = (const float*)d_in[11];
    const float* lk2  = (const float*)d_in[12];
    const float* Wl   = (const float*)d_in[13];
    const float* Wr   = (const float*)d_in[14];
    const float* Wp   = (const float*)d_in[15];
    const float* bp   = (const float*)d_in[16];
    float* out = (float*)d_out;
    float* ws  = (float*)d_ws;

    float* x = ws + WS_X;
    unsigned short* AHs = (unsigned short*)(ws + WS_AEXT);
    unsigned short* ALs = (unsigned short*)(ws + WS_AEXT + 3145728u);
    unsigned short* BHs = (unsigned short*)(ws + WS_BEXT);
    unsigned short* BLs = (unsigned short*)(ws + WS_BEXT + 3145728u);
    float* qn  = ws + WS_QN;
    float* sw  = ws + WS_SW;
    float* wsq = ws + WS_WSQ;
    float* bpP = ws + WS_BPP;
    unsigned short* WpF = (unsigned short*)(ws + WS_WPF);
    float* kraw = ws + WS_BIG;

    prep_wp<<<256, 256, 0, stream>>>(Wp, bp, WpF, bpP);
    k1_ln<<<49152, 256, 0, stream>>>(msa, ln_g, ln_b, x);
    k2_q<<<384, 128, 0, stream>>>(x, Wq, qn_g, qn_b, qn);
    for (int sc = 0; sc < 2; ++sc) {
        gemm_nt<<<dim3(768, 1), 256, 0, stream>>>(x + (size_t)sc * 98304 * 64, Wk, kraw, 64, 64, 64, 128);
        k3b_sw<<<256, 256, 0, stream>>>(kraw, qn, kn_g, kn_b, sw, sc);
    }
    k4_softmax<<<1, 512, 0, stream>>>(sw, lq1, lk1, lq2, lk2, wsq);
    k5_ab<<<dim3(384, 8), 256, 0, stream>>>(x, Wl, Wr, wsq, AHs, ALs, BHs, BLs);
    gemm_fused<<<9216, 256, 0, stream>>>(AHs, ALs, BHs, BLs, WpF, bpP, out);
}

// Round 5
// 1066.143 us; speedup vs baseline: 1.3206x; 1.3206x over previous
//
#include <hip/hip_runtime.h>
#include <hip/hip_bf16.h>
#include <math.h>

// B=1, S=512, N=384, D=64, H=32, DP=128, DQK=64
// ws layout (float offsets)
#define WS_X        0u          // x f32 [196608][64]                 = 12582912
#define WS_AEXT     12582912u   // AH frag bf16 [768*16][64][8] = 3145728 f, then AL same
#define WS_BEXT     18874368u   // BH, BL same
#define WS_QN       25165824u   // [2][384][64]
#define WS_SW       25214976u   // [2][512]
#define WS_WSQ      25216000u   // [512]
#define WS_BPP      25216512u   // [256]
#define WS_WPF      25216768u   // WpF bf16 frag-layout [2][16][32][64][8] = 262144 f
#define WS_BIG      25478912u   // kraw half [98304][128] f32 = 12582912 f

typedef __attribute__((ext_vector_type(8))) short bf16x8;
typedef __attribute__((ext_vector_type(4))) float f32x4;

union U4B8 { uint4 u4; unsigned u[4]; bf16x8 v; };

__device__ __forceinline__ unsigned short f2b(float x) {
    __hip_bfloat16 b = __float2bfloat16(x);
    return *reinterpret_cast<unsigned short*>(&b);
}
__device__ __forceinline__ float b2f(unsigned short u) {
    __hip_bfloat16 b = *reinterpret_cast<__hip_bfloat16*>(&u);
    return __bfloat162float(b);
}

#define GLDS(g, l) __builtin_amdgcn_global_load_lds(                                   \
    (const __attribute__((address_space(1))) unsigned int*)(g),                        \
    (__attribute__((address_space(3))) unsigned int*)(l), 16, 0, 0)

// ---------------- K1: LayerNorm over D=64, one wave per row ----------------
__global__ __launch_bounds__(256) void k1_ln(const float* __restrict__ msa,
                                             const float* __restrict__ g,
                                             const float* __restrict__ bb,
                                             float* __restrict__ x) {
    int row  = blockIdx.x * 4 + (threadIdx.x >> 6);
    int lane = threadIdx.x & 63;
    float v = msa[(size_t)row * 64 + lane];
    float sum = v;
    #pragma unroll
    for (int m = 1; m < 64; m <<= 1) sum += __shfl_xor(sum, m);
    float mean = sum * (1.0f / 64.0f);
    float dv = v - mean;
    float sq = dv * dv;
    #pragma unroll
    for (int m = 1; m < 64; m <<= 1) sq += __shfl_xor(sq, m);
    float r = rsqrtf(sq * (1.0f / 64.0f) + 1e-5f);
    x[(size_t)row * 64 + lane] = dv * r * g[lane] + bb[lane];
}

// ---------------- K2: q projection (s=0 rows) + LN ----------------
__global__ __launch_bounds__(128) void k2_q(const float* __restrict__ x,
                                            const float* __restrict__ Wq,
                                            const float* __restrict__ qg,
                                            const float* __restrict__ qb,
                                            float* __restrict__ qn) {
    int n = blockIdx.x;
    int t = threadIdx.x >> 6;
    int d = threadIdx.x & 63;
    const float* xr = x + (size_t)n * 64;
    const float* w  = Wq + (size_t)(t * 64 + d) * 64;
    float acc = 0.f;
    #pragma unroll 8
    for (int dd = 0; dd < 64; ++dd) acc += xr[dd] * w[dd];
    float sum = acc;
    #pragma unroll
    for (int m = 1; m < 64; m <<= 1) sum += __shfl_xor(sum, m);
    float mean = sum * (1.0f / 64.0f);
    float dv = acc - mean;
    float sq = dv * dv;
    #pragma unroll
    for (int m = 1; m < 64; m <<= 1) sq += __shfl_xor(sq, m);
    float r = rsqrtf(sq * (1.0f / 64.0f) + 1e-5f);
    qn[(size_t)(t * 384 + n) * 64 + d] = dv * r * qg[d] + qb[d];
}

// ---------------- fp32 NT GEMM (K3a only: x @ Wk^T) ----------------
__global__ __launch_bounds__(256) void gemm_nt(const float* __restrict__ A,
                                               const float* __restrict__ Bm,
                                               float* __restrict__ C,
                                               int K, int lda, int ldb, int ldc) {
    __shared__ float AsT[32][132];
    __shared__ float BsT[32][132];
    int t  = threadIdx.x;
    int m0 = blockIdx.x * 128, n0 = blockIdx.y * 128;
    int tr = t >> 4, tc = t & 15;
    float acc[8][8] = {};
    int rrow = t >> 3;
    int kk   = (t & 7) * 4;
    for (int k0 = 0; k0 < K; k0 += 32) {
        #pragma unroll
        for (int l = 0; l < 4; ++l) {
            int row = rrow + 32 * l;
            float4 va = *(const float4*)(A + (size_t)(m0 + row) * lda + k0 + kk);
            AsT[kk + 0][row] = va.x; AsT[kk + 1][row] = va.y;
            AsT[kk + 2][row] = va.z; AsT[kk + 3][row] = va.w;
            float4 vb = *(const float4*)(Bm + (size_t)(n0 + row) * ldb + k0 + kk);
            BsT[kk + 0][row] = vb.x; BsT[kk + 1][row] = vb.y;
            BsT[kk + 2][row] = vb.z; BsT[kk + 3][row] = vb.w;
        }
        __syncthreads();
        #pragma unroll 4
        for (int k = 0; k < 32; ++k) {
            float a[8], b[8];
            *(float4*)&a[0] = *(const float4*)&AsT[k][tr * 8];
            *(float4*)&a[4] = *(const float4*)&AsT[k][tr * 8 + 4];
            *(float4*)&b[0] = *(const float4*)&BsT[k][tc * 8];
            *(float4*)&b[4] = *(const float4*)&BsT[k][tc * 8 + 4];
            #pragma unroll
            for (int q = 0; q < 8; ++q)
                #pragma unroll
                for (int j = 0; j < 8; ++j)
                    acc[q][j] += a[q] * b[j];
        }
        __syncthreads();
    }
    #pragma unroll
    for (int q = 0; q < 8; ++q) {
        float* cp = C + (size_t)(m0 + tr * 8 + q) * ldc + n0 + tc * 8;
        *(float4*)cp       = make_float4(acc[q][0], acc[q][1], acc[q][2], acc[q][3]);
        *(float4*)(cp + 4) = make_float4(acc[q][4], acc[q][5], acc[q][6], acc[q][7]);
    }
}

// ---------------- K3b: k LN + dot with qn, reduce over n -> sw[2][512] ----------------
__global__ __launch_bounds__(256) void k3b_sw(const float* __restrict__ kraw,
                                              const float* __restrict__ qn,
                                              const float* __restrict__ kg,
                                              const float* __restrict__ kb,
                                              float* __restrict__ sw, int sc) {
    int sl   = blockIdx.x;
    int s    = sc * 256 + sl;
    int w    = threadIdx.x >> 6;
    int lane = threadIdx.x & 63;
    float gv = kg[lane], bv = kb[lane];
    float acc0 = 0.f, acc1 = 0.f;
    for (int n = w; n < 384; n += 4) {
        const float* row = kraw + ((size_t)sl * 384 + n) * 128;
        #pragma unroll
        for (int tt = 0; tt < 2; ++tt) {
            float v = row[tt * 64 + lane];
            float sum = v;
            #pragma unroll
            for (int m = 1; m < 64; m <<= 1) sum += __shfl_xor(sum, m);
            float mean = sum * (1.0f / 64.0f);
            float dv = v - mean;
            float sq = dv * dv;
            #pragma unroll
            for (int m = 1; m < 64; m <<= 1) sq += __shfl_xor(sq, m);
            float r  = rsqrtf(sq * (1.0f / 64.0f) + 1e-5f);
            float kn = dv * r * gv + bv;
            float p  = kn * qn[(size_t)(tt * 384 + n) * 64 + lane];
            #pragma unroll
            for (int m = 1; m < 64; m <<= 1) p += __shfl_xor(p, m);
            if (tt == 0) acc0 += p; else acc1 += p;
        }
    }
    __shared__ float red[8];
    if (lane == 0) { red[w] = acc0; red[4 + w] = acc1; }
    __syncthreads();
    if (threadIdx.x == 0) {
        float t0 = red[0] + red[1] + red[2] + red[3];
        float t1 = red[4] + red[5] + red[6] + red[7];
        sw[s]       = t0 * 0.125f / 384.0f;
        sw[512 + s] = t1 * 0.125f / 384.0f;
    }
}

// ---------------- K4: lambda, softmax over s, sqrt weights ----------------
__global__ __launch_bounds__(512) void k4_softmax(const float* __restrict__ sw,
                                                  const float* __restrict__ lq1,
                                                  const float* __restrict__ lk1,
                                                  const float* __restrict__ lq2,
                                                  const float* __restrict__ lk2,
                                                  float* __restrict__ wsq) {
    int s = threadIdx.x;
    float l1 = 0.f, l2 = 0.f;
    for (int i = 0; i < 64; ++i) { l1 += lq1[i] * lk1[i]; l2 += lq2[i] * lk2[i]; }
    float lam = expf(l1) - expf(l2) + 1.0f;
    float v = sw[s] - lam * sw[512 + s];
    __shared__ float red[512];
    red[s] = v;
    __syncthreads();
    for (int off = 256; off > 0; off >>= 1) {
        if (s < off) red[s] = fmaxf(red[s], red[s + off]);
        __syncthreads();
    }
    float mx = red[0];
    __syncthreads();
    float e = expf(v - mx);
    red[s] = e;
    __syncthreads();
    for (int off = 256; off > 0; off >>= 1) {
        if (s < off) red[s] += red[s + off];
        __syncthreads();
    }
    wsq[s] = sqrtf(e / red[0] + 1e-32f);
}

// ---------------- K5: build A/B hi-lo splits in MFMA-frag-native layout ----------------
// Frag layout: array[(panel*16 + kstep)*64 + slot][8] where panel = m>>4,
// kstep = s>>5, slot = (m&15) | (((s>>3)&3)<<4), element = s&7.
__global__ __launch_bounds__(256) void k5_ab(const float* __restrict__ x,
                                             const float* __restrict__ Wl,
                                             const float* __restrict__ Wr,
                                             const float* __restrict__ wsq,
                                             unsigned short* __restrict__ AHo,
                                             unsigned short* __restrict__ ALo,
                                             unsigned short* __restrict__ BHo,
                                             unsigned short* __restrict__ BLo) {
    int i  = blockIdx.x;
    int s0 = blockIdx.y * 64;
    int t  = threadIdx.x;
    __shared__ __align__(16) float wl[2048], wr[2048];
    __shared__ float xT[64][69];
    ((float4*)wl)[t * 2]     = ((const float4*)Wl)[t * 2];
    ((float4*)wl)[t * 2 + 1] = ((const float4*)Wl)[t * 2 + 1];
    ((float4*)wr)[t * 2]     = ((const float4*)Wr)[t * 2];
    ((float4*)wr)[t * 2 + 1] = ((const float4*)Wr)[t * 2 + 1];
    {
        int s_l = t >> 2, d0 = (t & 3) * 16;
        const float* xr = x + ((size_t)(s0 + s_l) * 384 + i) * 64 + d0;
        #pragma unroll
        for (int j = 0; j < 4; ++j) {
            float4 v = *(const float4*)(xr + j * 4);
            xT[d0 + j * 4 + 0][s_l] = v.x; xT[d0 + j * 4 + 1][s_l] = v.y;
            xT[d0 + j * 4 + 2][s_l] = v.z; xT[d0 + j * 4 + 3][s_l] = v.w;
        }
    }
    __syncthreads();
    int c = t >> 3, so = (t & 7) * 8;
    float aa[8] = {}, bb2[8] = {};
    #pragma unroll 8
    for (int d = 0; d < 64; ++d) {
        float wlv = wl[c * 64 + d], wrv = wr[c * 64 + d];
        #pragma unroll
        for (int q = 0; q < 8; ++q) {
            float xv = xT[d][so + q];
            aa[q]  += xv * wlv;
            bb2[q] += xv * wrv;
        }
    }
    #pragma unroll
    for (int q = 0; q < 8; ++q) {
        float wq = wsq[s0 + so + q];
        aa[q] *= wq; bb2[q] *= wq;
    }
    int m = i * 32 + c;
    int s = s0 + so;
    size_t idx = (((size_t)(m >> 4) * 16 + (s >> 5)) * 64 + ((m & 15) | (((s >> 3) & 3) << 4))) * 8;
    {
        unsigned short h[8], l[8];
        #pragma unroll
        for (int q = 0; q < 8; ++q) { h[q] = f2b(aa[q]); l[q] = f2b(aa[q] - b2f(h[q])); }
        *(uint4*)&AHo[idx] = make_uint4((unsigned)h[0] | ((unsigned)h[1] << 16), (unsigned)h[2] | ((unsigned)h[3] << 16),
                                        (unsigned)h[4] | ((unsigned)h[5] << 16), (unsigned)h[6] | ((unsigned)h[7] << 16));
        *(uint4*)&ALo[idx] = make_uint4((unsigned)l[0] | ((unsigned)l[1] << 16), (unsigned)l[2] | ((unsigned)l[3] << 16),
                                        (unsigned)l[4] | ((unsigned)l[5] << 16), (unsigned)l[6] | ((unsigned)l[7] << 16));
    }
    {
        unsigned short h[8], l[8];
        #pragma unroll
        for (int q = 0; q < 8; ++q) { h[q] = f2b(bb2[q]); l[q] = f2b(bb2[q] - b2f(h[q])); }
        *(uint4*)&BHo[idx] = make_uint4((unsigned)h[0] | ((unsigned)h[1] << 16), (unsigned)h[2] | ((unsigned)h[3] << 16),
                                        (unsigned)h[4] | ((unsigned)h[5] << 16), (unsigned)h[6] | ((unsigned)h[7] << 16));
        *(uint4*)&BLo[idx] = make_uint4((unsigned)l[0] | ((unsigned)l[1] << 16), (unsigned)l[2] | ((unsigned)l[3] << 16),
                                        (unsigned)l[4] | ((unsigned)l[5] << 16), (unsigned)l[6] | ((unsigned)l[7] << 16));
    }
}

// ---------------- prep: WpF frag layout [bsel][nb][kstep][lane][8] + bpP ----------------
__global__ __launch_bounds__(256) void prep_wp(const float* __restrict__ Wp,
                                               const float* __restrict__ bp,
                                               unsigned short* __restrict__ WpF,
                                               float* __restrict__ bpP) {
    int gid = blockIdx.x * 256 + threadIdx.x;      // 256 blocks -> 65536 groups
    int lane  = gid & 63;
    int kstep = (gid >> 6) & 31;
    int nb    = (gid >> 11) & 15;
    int bsel  = gid >> 15;
    int rl = lane & 15, kg = lane >> 4;
    int urow = nb * 16 + rl;
    int srow = (urow & 1) ? 128 + (urow >> 1) : (urow >> 1);
    int k0 = kstep * 32 + kg * 8;
    const float* src = Wp + (size_t)srow * 1024 + k0;
    unsigned short o[8];
    #pragma unroll
    for (int e = 0; e < 8; ++e) {
        float w = src[e];
        unsigned short h = f2b(w);
        o[e] = bsel ? f2b(w - b2f(h)) : h;
    }
    *(uint4*)&WpF[(size_t)gid * 8] = make_uint4(
        (unsigned)o[0] | ((unsigned)o[1] << 16), (unsigned)o[2] | ((unsigned)o[3] << 16),
        (unsigned)o[4] | ((unsigned)o[5] << 16), (unsigned)o[6] | ((unsigned)o[7] << 16));
    if (blockIdx.x == 0) {
        int tt = threadIdx.x;
        bpP[tt] = bp[(tt & 1) ? 128 + (tt >> 1) : (tt >> 1)];
    }
}

// ---------------- FUSED: outer tile (dbuf BK=32, bf16x3) + Wp projection + SwiGLU ----------------
// grid (96,96). LDS = 64KB exactly: 2 bufs x {AH,AL,BH,BL} x 8KB, pa [16][1024] u32 aliased.
__global__ __launch_bounds__(256) void gemm_fused(const unsigned short* __restrict__ AH,
                                                  const unsigned short* __restrict__ AL,
                                                  const unsigned short* __restrict__ BHm,
                                                  const unsigned short* __restrict__ BLm,
                                                  const unsigned short* __restrict__ WpF,
                                                  const float* __restrict__ bpP,
                                                  float* __restrict__ out) {
    __shared__ __align__(16) unsigned char smem[65536];
    unsigned* pa = (unsigned*)smem;                       // [16][1024] packed hi|lo u32

    const int t = threadIdx.x;
    const int wave = t >> 6, lane = t & 63;
    const int bx = blockIdx.x, by = blockIdx.y;
    const int m0 = bx * 128, n0 = by * 128;
    const int wm = (wave & 1) * 64, wn = (wave >> 1) * 64;
    const int kgrp = lane >> 4, rl = lane & 15;
    f32x4 acc[4][4] = {};

    // wave w stages array w: 0->AH, 1->AL, 2->BH, 3->BL; frag (pane,kt) is 1KB.
    const unsigned short* srcArr = (wave == 0) ? AH : (wave == 1) ? AL : (wave == 2) ? BHm : BLm;
    const unsigned short* srcBase = srcArr + ((size_t)(((wave < 2) ? m0 : n0) >> 4) * 16) * 512 + lane * 8;
    unsigned short* dstW = (unsigned short*)smem + wave * 4096;   // shorts; +16384 for buf1

    // prologue: stage kt=0 into buf0
    #pragma unroll
    for (int pane = 0; pane < 8; ++pane)
        GLDS(srcBase + (size_t)pane * 8192, dstW + pane * 512);
    __syncthreads();

    #pragma unroll 2
    for (int kt = 0; kt < 16; ++kt) {
        if (kt < 15) {   // stage next half-tile into the other buffer (overlaps compute)
            unsigned short* dst = dstW + ((kt + 1) & 1) * 16384;
            const unsigned short* s2 = srcBase + (size_t)(kt + 1) * 512;
            #pragma unroll
            for (int pane = 0; pane < 8; ++pane)
                GLDS(s2 + (size_t)pane * 8192, dst + pane * 512);
        }
        const int cb = (kt & 1) * 32768;   // bytes
        bf16x8 aHf[4], aLf[4], bHf[4], bLf[4];
        #pragma unroll
        for (int f = 0; f < 4; ++f) {
            const int pA = ((wm >> 4) + f) * 1024;
            aHf[f] = *(const bf16x8*)(smem + cb + pA + lane * 16);
            aLf[f] = *(const bf16x8*)(smem + cb + 8192 + pA + lane * 16);
            const int pB = ((wn >> 4) + f) * 1024;
            bHf[f] = *(const bf16x8*)(smem + cb + 16384 + pB + lane * 16);
            bLf[f] = *(const bf16x8*)(smem + cb + 24576 + pB + lane * 16);
        }
        #pragma unroll
        for (int mf = 0; mf < 4; ++mf)
            #pragma unroll
            for (int nf = 0; nf < 4; ++nf) {
                acc[mf][nf] = __builtin_amdgcn_mfma_f32_16x16x32_bf16(aHf[mf], bHf[nf], acc[mf][nf], 0, 0, 0);
                acc[mf][nf] = __builtin_amdgcn_mfma_f32_16x16x32_bf16(aLf[mf], bHf[nf], acc[mf][nf], 0, 0, 0);
                acc[mf][nf] = __builtin_amdgcn_mfma_f32_16x16x32_bf16(aHf[mf], bLf[nf], acc[mf][nf], 0, 0, 0);
            }
        __syncthreads();   // drains the prefetch GLDS (vmcnt0) + makes buf visible
    }

    // ---- spill outer tile to pa as packed hi|lo bf16 (XOR-swizzled, 4-way) ----
    #pragma unroll
    for (int mf = 0; mf < 4; ++mf) {
        #pragma unroll
        for (int nf = 0; nf < 4; ++nf) {
            #pragma unroll
            for (int r = 0; r < 4; ++r) {
                int mloc = wm + mf * 16 + kgrp * 4 + r;
                int nloc = wn + nf * 16 + rl;
                int p = ((mloc >> 5) << 2) | (nloc >> 5);
                int k = ((mloc & 31) << 5) | (nloc & 31);
                float v = acc[mf][nf][r];
                unsigned short h = f2b(v);
                unsigned short l = f2b(v - b2f(h));
                pa[(p << 10) + (k ^ ((p & 3) << 3))] = (unsigned)h | ((unsigned)l << 16);
            }
        }
    }
    __syncthreads();

    // ---- epilogue GEMM: [16 pairs] x WpF^T, single pass over all 3 sections ----
    f32x4 acc2[4] = {};
    const unsigned* paRow = pa + (rl << 10);
    const int kg8 = kgrp * 8;
    #pragma unroll 4
    for (int ks = 0; ks < 32; ++ks) {
        U4B8 ua0, ua1, aHf, aLf;
        int kb = (ks * 32 + kg8) ^ ((rl & 3) << 3);
        ua0.u4 = *(const uint4*)(paRow + kb);
        ua1.u4 = *(const uint4*)(paRow + kb + 4);
        aHf.u[0] = (ua0.u[0] & 0xffffu) | (ua0.u[1] << 16);
        aHf.u[1] = (ua0.u[2] & 0xffffu) | (ua0.u[3] << 16);
        aHf.u[2] = (ua1.u[0] & 0xffffu) | (ua1.u[1] << 16);
        aHf.u[3] = (ua1.u[2] & 0xffffu) | (ua1.u[3] << 16);
        aLf.u[0] = (ua0.u[0] >> 16) | (ua0.u[1] & 0xffff0000u);
        aLf.u[1] = (ua0.u[2] >> 16) | (ua0.u[3] & 0xffff0000u);
        aLf.u[2] = (ua1.u[0] >> 16) | (ua1.u[1] & 0xffff0000u);
        aLf.u[3] = (ua1.u[2] >> 16) | (ua1.u[3] & 0xffff0000u);
        bf16x8 bHf[4], bLf[4];
        #pragma unroll
        for (int nf = 0; nf < 4; ++nf) {
            const int nb = wave * 4 + nf;
            bHf[nf] = *(const bf16x8*)&WpF[(size_t)((nb * 32 + ks) * 64 + lane) * 8];
            bLf[nf] = *(const bf16x8*)&WpF[(size_t)(((16 + nb) * 32 + ks) * 64 + lane) * 8];
        }
        #pragma unroll
        for (int nf = 0; nf < 4; ++nf) {
            acc2[nf] = __builtin_amdgcn_mfma_f32_16x16x32_bf16(aHf.v, bHf[nf], acc2[nf], 0, 0, 0);
            acc2[nf] = __builtin_amdgcn_mfma_f32_16x16x32_bf16(aLf.v, bHf[nf], acc2[nf], 0, 0, 0);
            acc2[nf] = __builtin_amdgcn_mfma_f32_16x16x32_bf16(aHf.v, bLf[nf], acc2[nf], 0, 0, 0);
        }
    }

    // ---- bias + SwiGLU + store ----
    const int parity = rl & 1;
    #pragma unroll
    for (int nf = 0; nf < 4; ++nf) {
        const int np = wave * 64 + nf * 16 + rl;   // logical u-row (interleaved val/gate)
        const float bias = bpP[np];
        const int ocol = np >> 1;
        #pragma unroll
        for (int r = 0; r < 4; ++r) {
            float own = acc2[nf][r] + bias;
            float oth = __shfl_xor(own, 1);
            float v = parity ? oth : own;
            float g = parity ? own : oth;
            float res = v * (g / (1.0f + expf(-g)));
            if (parity == (r >> 1)) {
                int p = kgrp * 4 + r;               // pair index = C row
                int i = bx * 4 + (p >> 2);
                int j = by * 4 + (p & 3);
                out[((size_t)i * 384 + j) * 128 + ocol] = res;
            }
        }
    }
}

extern "C" void kernel_launch(void* const* d_in, const int* in_sizes, int n_in,
                              void* d_out, int out_size, void* d_ws, size_t ws_size,
                              hipStream_t stream) {
    const float* msa  = (const float*)d_in[0];
    const float* ln_g = (const float*)d_in[1];
    const float* ln_b = (const float*)d_in[2];
    const float* Wq   = (const float*)d_in[3];
    const float* Wk   = (const float*)d_in[4];
    const float* qn_g = (const float*)d_in[5];
    const float* qn_b = (const float*)d_in[6];
    const float* kn_g = (const float*)d_in[7];
    const float* kn_b = (const float*)d_in[8];
    const float* lq1  = (const float*)d_in[9];
    const float* lk1  = (const float*)d_in[10];
    const float* lq2  = (const float*)d_in[11];
    const float* lk2  = (const float*)d_in[12];
    const float* Wl   = (const float*)d_in[13];
    const float* Wr   = (const float*)d_in[14];
    const float* Wp   = (const float*)d_in[15];
    const float* bp   = (const float*)d_in[16];
    float* out = (float*)d_out;
    float* ws  = (float*)d_ws;

    float* x = ws + WS_X;
    unsigned short* AHs = (unsigned short*)(ws + WS_AEXT);
    unsigned short* ALs = (unsigned short*)(ws + WS_AEXT + 3145728u);
    unsigned short* BHs = (unsigned short*)(ws + WS_BEXT);
    unsigned short* BLs = (unsigned short*)(ws + WS_BEXT + 3145728u);
    float* qn  = ws + WS_QN;
    float* sw  = ws + WS_SW;
    float* wsq = ws + WS_WSQ;
    float* bpP = ws + WS_BPP;
    unsigned short* WpF = (unsigned short*)(ws + WS_WPF);
    float* kraw = ws + WS_BIG;

    prep_wp<<<256, 256, 0, stream>>>(Wp, bp, WpF, bpP);
    k1_ln<<<49152, 256, 0, stream>>>(msa, ln_g, ln_b, x);
    k2_q<<<384, 128, 0, stream>>>(x, Wq, qn_g, qn_b, qn);
    for (int sc = 0; sc < 2; ++sc) {
        gemm_nt<<<dim3(768, 1), 256, 0, stream>>>(x + (size_t)sc * 98304 * 64, Wk, kraw, 64, 64, 64, 128);
        k3b_sw<<<256, 256, 0, stream>>>(kraw, qn, kn_g, kn_b, sw, sc);
    }
    k4_softmax<<<1, 512, 0, stream>>>(sw, lq1, lk1, lq2, lk2, wsq);
    k5_ab<<<dim3(384, 8), 256, 0, stream>>>(x, Wl, Wr, wsq, AHs, ALs, BHs, BLs);
    gemm_fused<<<dim3(96, 96), 256, 0, stream>>>(AHs, ALs, BHs, BLs, WpF, bpP, out);
}

// Round 6
// 848.519 us; speedup vs baseline: 1.6593x; 1.2565x over previous
//
#include <hip/hip_runtime.h>
#include <hip/hip_bf16.h>
#include <math.h>

// B=1, S=512, N=384, D=64, H=32, DP=128, DQK=64
// ws layout (float offsets)
#define WS_X        0u          // x f32 [196608][64]                 = 12582912
#define WS_AEXT     12582912u   // AH frag bf16 [768*16][64][8] = 3145728 f, then AL same
#define WS_BEXT     18874368u   // BH, BL same
#define WS_QG       25165824u   // qg [2][384][64] = 49152
#define WS_SQG      25214976u   // [768]
#define WS_SQB      25215744u   // [768]
#define WS_PART     25216512u   // partial dots [2][512][3] = 3072
#define WS_WSQ      25219584u   // [512]
#define WS_BPP      25220096u   // [256]
#define WS_WPF      25220352u   // WpF bf16 frag-layout [2][16][32][64][8] = 262144 f

typedef __attribute__((ext_vector_type(8))) short bf16x8;
typedef __attribute__((ext_vector_type(4))) float f32x4;

union U4B8 { uint4 u4; unsigned u[4]; bf16x8 v; };

__device__ __forceinline__ unsigned short f2b(float x) {
    __hip_bfloat16 b = __float2bfloat16(x);
    return *reinterpret_cast<unsigned short*>(&b);
}
__device__ __forceinline__ float b2f(unsigned short u) {
    __hip_bfloat16 b = *reinterpret_cast<__hip_bfloat16*>(&u);
    return __bfloat162float(b);
}

#define GLDS(g, l) __builtin_amdgcn_global_load_lds(                                   \
    (const __attribute__((address_space(1))) unsigned int*)(g),                        \
    (__attribute__((address_space(3))) unsigned int*)(l), 16, 0, 0)

// ---------------- K1: LayerNorm over D=64, float4-vectorized (16 rows/block) ----------------
__global__ __launch_bounds__(256) void k1_ln(const float* __restrict__ msa,
                                             const float* __restrict__ g,
                                             const float* __restrict__ bb,
                                             float* __restrict__ x) {
    int row = blockIdx.x * 16 + (threadIdx.x >> 4);
    int l16 = threadIdx.x & 15;
    float4 v = ((const float4*)msa)[(size_t)row * 16 + l16];
    float sum = v.x + v.y + v.z + v.w;
    #pragma unroll
    for (int m = 1; m < 16; m <<= 1) sum += __shfl_xor(sum, m);
    float mean = sum * (1.0f / 64.0f);
    float4 dv = make_float4(v.x - mean, v.y - mean, v.z - mean, v.w - mean);
    float sq = dv.x * dv.x + dv.y * dv.y + dv.z * dv.z + dv.w * dv.w;
    #pragma unroll
    for (int m = 1; m < 16; m <<= 1) sq += __shfl_xor(sq, m);
    float r = rsqrtf(sq * (1.0f / 64.0f) + 1e-5f);
    float4 g4 = ((const float4*)g)[l16];
    float4 b4 = ((const float4*)bb)[l16];
    ((float4*)x)[(size_t)row * 16 + l16] = make_float4(
        dv.x * r * g4.x + b4.x, dv.y * r * g4.y + b4.y,
        dv.z * r * g4.z + b4.z, dv.w * r * g4.w + b4.w);
}

// ---------------- K2: q projection + LN, emit qg = qn*kn_g, Sqg, Sqb ----------------
__global__ __launch_bounds__(128) void k2_q(const float* __restrict__ x,
                                            const float* __restrict__ Wq,
                                            const float* __restrict__ qg_,
                                            const float* __restrict__ qb_,
                                            const float* __restrict__ kg_,
                                            const float* __restrict__ kb_,
                                            float* __restrict__ qgOut,
                                            float* __restrict__ SqgOut,
                                            float* __restrict__ SqbOut) {
    int n = blockIdx.x;
    int tt = threadIdx.x >> 6;
    int d = threadIdx.x & 63;
    const float* xr = x + (size_t)n * 64;
    const float* w  = Wq + (size_t)(tt * 64 + d) * 64;
    float acc = 0.f;
    #pragma unroll 8
    for (int dd = 0; dd < 64; ++dd) acc += xr[dd] * w[dd];
    float sum = acc;
    #pragma unroll
    for (int m = 1; m < 64; m <<= 1) sum += __shfl_xor(sum, m);
    float mean = sum * (1.0f / 64.0f);
    float dv = acc - mean;
    float sq = dv * dv;
    #pragma unroll
    for (int m = 1; m < 64; m <<= 1) sq += __shfl_xor(sq, m);
    float r = rsqrtf(sq * (1.0f / 64.0f) + 1e-5f);
    float qnv = dv * r * qg_[d] + qb_[d];
    float qgv = qnv * kg_[d];
    float sb  = qnv * kb_[d];
    float sg  = qgv;
    #pragma unroll
    for (int m = 1; m < 64; m <<= 1) { sg += __shfl_xor(sg, m); sb += __shfl_xor(sb, m); }
    qgOut[(size_t)(tt * 384 + n) * 64 + d] = qgv;
    if (d == 0) { SqgOut[tt * 384 + n] = sg; SqbOut[tt * 384 + n] = sb; }
}

// ---------------- gemm_k3: kraw tile (fp32 GEMM) + LN-dot epilogue -> partials ----------------
// grid 1536: block b -> rows m0=b*128 of x (one s, one n-chunk of 128), cols = all 128 Wk rows.
__global__ __launch_bounds__(256) void gemm_k3(const float* __restrict__ X,
                                               const float* __restrict__ Wk,
                                               const float* __restrict__ qg,
                                               const float* __restrict__ Sqg,
                                               const float* __restrict__ Sqb,
                                               float* __restrict__ part) {
    __shared__ __align__(16) char smem[65536];
    float (*AsT)[132] = (float(*)[132])smem;
    float (*BsT)[132] = (float(*)[132])(smem + 16896);
    float* kbuf = (float*)smem;   // aliases AsT/BsT after GEMM completes

    int t  = threadIdx.x;
    int m0 = blockIdx.x * 128;
    int s  = m0 / 384;
    int nchunk = (m0 - s * 384) >> 7;
    int tr = t >> 4, tc = t & 15;
    float acc[8][8] = {};
    int rrow = t >> 3;
    int kk   = (t & 7) * 4;
    for (int k0 = 0; k0 < 64; k0 += 32) {
        #pragma unroll
        for (int l = 0; l < 4; ++l) {
            int row = rrow + 32 * l;
            float4 va = *(const float4*)(X + (size_t)(m0 + row) * 64 + k0 + kk);
            AsT[kk + 0][row] = va.x; AsT[kk + 1][row] = va.y;
            AsT[kk + 2][row] = va.z; AsT[kk + 3][row] = va.w;
            float4 vb = *(const float4*)(Wk + (size_t)row * 64 + k0 + kk);
            BsT[kk + 0][row] = vb.x; BsT[kk + 1][row] = vb.y;
            BsT[kk + 2][row] = vb.z; BsT[kk + 3][row] = vb.w;
        }
        __syncthreads();
        #pragma unroll 4
        for (int k = 0; k < 32; ++k) {
            float a[8], b[8];
            *(float4*)&a[0] = *(const float4*)&AsT[k][tr * 8];
            *(float4*)&a[4] = *(const float4*)&AsT[k][tr * 8 + 4];
            *(float4*)&b[0] = *(const float4*)&BsT[k][tc * 8];
            *(float4*)&b[4] = *(const float4*)&BsT[k][tc * 8 + 4];
            #pragma unroll
            for (int q = 0; q < 8; ++q)
                #pragma unroll
                for (int j = 0; j < 8; ++j)
                    acc[q][j] += a[q] * b[j];
        }
        __syncthreads();
    }
    // spill kraw tile to kbuf, XOR-swizzled 16B units: byte = m*512 + ((unit*16) ^ ((m&15)<<4))
    #pragma unroll
    for (int q = 0; q < 8; ++q) {
        int m = tr * 8 + q;
        int swz = (m & 15) << 4;
        int b0 = m * 512 + (((tc * 2) * 16) ^ swz);
        int b1 = m * 512 + (((tc * 2 + 1) * 16) ^ swz);
        *(float4*)((char*)kbuf + b0) = make_float4(acc[q][0], acc[q][1], acc[q][2], acc[q][3]);
        *(float4*)((char*)kbuf + b1) = make_float4(acc[q][4], acc[q][5], acc[q][6], acc[q][7]);
    }
    __syncthreads();
    // per-thread LN + dot for (row r, half tt)
    int r  = t & 127;
    int tt = t >> 7;
    int n  = nchunk * 128 + r;
    const char* base = (const char*)kbuf + r * 512;
    const float4* qgp = (const float4*)(qg + ((size_t)(tt * 384 + n)) * 64);
    int swz = (r & 15) << 4;
    float s1 = 0.f, s2 = 0.f, s3 = 0.f;
    #pragma unroll
    for (int i = 0; i < 16; ++i) {
        float4 kv = *(const float4*)(base + ((((tt * 16 + i) * 16) ^ swz)));
        float4 qv = qgp[i];
        s1 += kv.x + kv.y + kv.z + kv.w;
        s2 += kv.x * kv.x + kv.y * kv.y + kv.z * kv.z + kv.w * kv.w;
        s3 += kv.x * qv.x + kv.y * qv.y + kv.z * qv.z + kv.w * qv.w;
    }
    float mu  = s1 * (1.0f / 64.0f);
    float var = s2 * (1.0f / 64.0f) - mu * mu;
    float rln = rsqrtf(var + 1e-5f);
    float dot = rln * (s3 - mu * Sqg[tt * 384 + n]) + Sqb[tt * 384 + n];
    #pragma unroll
    for (int m = 1; m < 64; m <<= 1) dot += __shfl_xor(dot, m);
    __syncthreads();
    if ((t & 63) == 0) kbuf[t >> 6] = dot;
    __syncthreads();
    if (t == 0) part[((size_t)0 * 512 + s) * 3 + nchunk] = kbuf[0] + kbuf[1];
    if (t == 1) part[((size_t)1 * 512 + s) * 3 + nchunk] = kbuf[2] + kbuf[3];
}

// ---------------- K4: lambda, softmax over s, sqrt weights (reads partials) ----------------
__global__ __launch_bounds__(512) void k4_softmax(const float* __restrict__ part,
                                                  const float* __restrict__ lq1,
                                                  const float* __restrict__ lk1,
                                                  const float* __restrict__ lq2,
                                                  const float* __restrict__ lk2,
                                                  float* __restrict__ wsq) {
    int s = threadIdx.x;
    float l1 = 0.f, l2 = 0.f;
    for (int i = 0; i < 64; ++i) { l1 += lq1[i] * lk1[i]; l2 += lq2[i] * lk2[i]; }
    float lam = expf(l1) - expf(l2) + 1.0f;
    const float c = 0.125f / 384.0f;
    float a0 = (part[s * 3] + part[s * 3 + 1] + part[s * 3 + 2]) * c;
    float a1 = (part[(512 + s) * 3] + part[(512 + s) * 3 + 1] + part[(512 + s) * 3 + 2]) * c;
    float v = a0 - lam * a1;
    __shared__ float red[512];
    red[s] = v;
    __syncthreads();
    for (int off = 256; off > 0; off >>= 1) {
        if (s < off) red[s] = fmaxf(red[s], red[s + off]);
        __syncthreads();
    }
    float mx = red[0];
    __syncthreads();
    float e = expf(v - mx);
    red[s] = e;
    __syncthreads();
    for (int off = 256; off > 0; off >>= 1) {
        if (s < off) red[s] += red[s + off];
        __syncthreads();
    }
    wsq[s] = sqrtf(e / red[0] + 1e-32f);
}

// ---------------- K5: build A/B hi-lo splits in MFMA-frag-native layout ----------------
__global__ __launch_bounds__(256) void k5_ab(const float* __restrict__ x,
                                             const float* __restrict__ Wl,
                                             const float* __restrict__ Wr,
                                             const float* __restrict__ wsq,
                                             unsigned short* __restrict__ AHo,
                                             unsigned short* __restrict__ ALo,
                                             unsigned short* __restrict__ BHo,
                                             unsigned short* __restrict__ BLo) {
    int i  = blockIdx.x;
    int s0 = blockIdx.y * 64;
    int t  = threadIdx.x;
    __shared__ __align__(16) float wl[2048], wr[2048];
    __shared__ float xT[64][69];
    ((float4*)wl)[t * 2]     = ((const float4*)Wl)[t * 2];
    ((float4*)wl)[t * 2 + 1] = ((const float4*)Wl)[t * 2 + 1];
    ((float4*)wr)[t * 2]     = ((const float4*)Wr)[t * 2];
    ((float4*)wr)[t * 2 + 1] = ((const float4*)Wr)[t * 2 + 1];
    {
        int s_l = t >> 2, d0 = (t & 3) * 16;
        const float* xr = x + ((size_t)(s0 + s_l) * 384 + i) * 64 + d0;
        #pragma unroll
        for (int j = 0; j < 4; ++j) {
            float4 v = *(const float4*)(xr + j * 4);
            xT[d0 + j * 4 + 0][s_l] = v.x; xT[d0 + j * 4 + 1][s_l] = v.y;
            xT[d0 + j * 4 + 2][s_l] = v.z; xT[d0 + j * 4 + 3][s_l] = v.w;
        }
    }
    __syncthreads();
    int c = t >> 3, so = (t & 7) * 8;
    float aa[8] = {}, bb2[8] = {};
    #pragma unroll 8
    for (int d = 0; d < 64; ++d) {
        float wlv = wl[c * 64 + d], wrv = wr[c * 64 + d];
        #pragma unroll
        for (int q = 0; q < 8; ++q) {
            float xv = xT[d][so + q];
            aa[q]  += xv * wlv;
            bb2[q] += xv * wrv;
        }
    }
    #pragma unroll
    for (int q = 0; q < 8; ++q) {
        float wq = wsq[s0 + so + q];
        aa[q] *= wq; bb2[q] *= wq;
    }
    int m = i * 32 + c;
    int s = s0 + so;
    size_t idx = (((size_t)(m >> 4) * 16 + (s >> 5)) * 64 + ((m & 15) | (((s >> 3) & 3) << 4))) * 8;
    {
        unsigned short h[8], l[8];
        #pragma unroll
        for (int q = 0; q < 8; ++q) { h[q] = f2b(aa[q]); l[q] = f2b(aa[q] - b2f(h[q])); }
        *(uint4*)&AHo[idx] = make_uint4((unsigned)h[0] | ((unsigned)h[1] << 16), (unsigned)h[2] | ((unsigned)h[3] << 16),
                                        (unsigned)h[4] | ((unsigned)h[5] << 16), (unsigned)h[6] | ((unsigned)h[7] << 16));
        *(uint4*)&ALo[idx] = make_uint4((unsigned)l[0] | ((unsigned)l[1] << 16), (unsigned)l[2] | ((unsigned)l[3] << 16),
                                        (unsigned)l[4] | ((unsigned)l[5] << 16), (unsigned)l[6] | ((unsigned)l[7] << 16));
    }
    {
        unsigned short h[8], l[8];
        #pragma unroll
        for (int q = 0; q < 8; ++q) { h[q] = f2b(bb2[q]); l[q] = f2b(bb2[q] - b2f(h[q])); }
        *(uint4*)&BHo[idx] = make_uint4((unsigned)h[0] | ((unsigned)h[1] << 16), (unsigned)h[2] | ((unsigned)h[3] << 16),
                                        (unsigned)h[4] | ((unsigned)h[5] << 16), (unsigned)h[6] | ((unsigned)h[7] << 16));
        *(uint4*)&BLo[idx] = make_uint4((unsigned)l[0] | ((unsigned)l[1] << 16), (unsigned)l[2] | ((unsigned)l[3] << 16),
                                        (unsigned)l[4] | ((unsigned)l[5] << 16), (unsigned)l[6] | ((unsigned)l[7] << 16));
    }
}

// ---------------- prep: WpF frag layout [bsel][nb][kstep][lane][8] + bpP ----------------
__global__ __launch_bounds__(256) void prep_wp(const float* __restrict__ Wp,
                                               const float* __restrict__ bp,
                                               unsigned short* __restrict__ WpF,
                                               float* __restrict__ bpP) {
    int gid = blockIdx.x * 256 + threadIdx.x;
    int lane  = gid & 63;
    int kstep = (gid >> 6) & 31;
    int nb    = (gid >> 11) & 15;
    int bsel  = gid >> 15;
    int rl = lane & 15, kg = lane >> 4;
    int urow = nb * 16 + rl;
    int srow = (urow & 1) ? 128 + (urow >> 1) : (urow >> 1);
    int k0 = kstep * 32 + kg * 8;
    const float* src = Wp + (size_t)srow * 1024 + k0;
    unsigned short o[8];
    #pragma unroll
    for (int e = 0; e < 8; ++e) {
        float w = src[e];
        unsigned short h = f2b(w);
        o[e] = bsel ? f2b(w - b2f(h)) : h;
    }
    *(uint4*)&WpF[(size_t)gid * 8] = make_uint4(
        (unsigned)o[0] | ((unsigned)o[1] << 16), (unsigned)o[2] | ((unsigned)o[3] << 16),
        (unsigned)o[4] | ((unsigned)o[5] << 16), (unsigned)o[6] | ((unsigned)o[7] << 16));
    if (blockIdx.x == 0) {
        int tt = threadIdx.x;
        bpP[tt] = bp[(tt & 1) ? 128 + (tt >> 1) : (tt >> 1)];
    }
}

// ---------------- FUSED: outer tile (dbuf BK=32, bf16x3) + Wp projection + SwiGLU ----------------
__global__ __launch_bounds__(256) void gemm_fused(const unsigned short* __restrict__ AH,
                                                  const unsigned short* __restrict__ AL,
                                                  const unsigned short* __restrict__ BHm,
                                                  const unsigned short* __restrict__ BLm,
                                                  const unsigned short* __restrict__ WpF,
                                                  const float* __restrict__ bpP,
                                                  float* __restrict__ out) {
    __shared__ __align__(16) unsigned char smem[65536];
    unsigned* pa = (unsigned*)smem;                       // [16][1024] packed hi|lo u32

    const int t = threadIdx.x;
    const int wave = t >> 6, lane = t & 63;
    const int bx = blockIdx.x, by = blockIdx.y;
    const int m0 = bx * 128, n0 = by * 128;
    const int wm = (wave & 1) * 64, wn = (wave >> 1) * 64;
    const int kgrp = lane >> 4, rl = lane & 15;
    f32x4 acc[4][4] = {};

    const unsigned short* srcArr = (wave == 0) ? AH : (wave == 1) ? AL : (wave == 2) ? BHm : BLm;
    const unsigned short* srcBase = srcArr + ((size_t)(((wave < 2) ? m0 : n0) >> 4) * 16) * 512 + lane * 8;
    unsigned short* dstW = (unsigned short*)smem + wave * 4096;

    #pragma unroll
    for (int pane = 0; pane < 8; ++pane)
        GLDS(srcBase + (size_t)pane * 8192, dstW + pane * 512);
    __syncthreads();

    #pragma unroll 2
    for (int kt = 0; kt < 16; ++kt) {
        if (kt < 15) {
            unsigned short* dst = dstW + ((kt + 1) & 1) * 16384;
            const unsigned short* s2 = srcBase + (size_t)(kt + 1) * 512;
            #pragma unroll
            for (int pane = 0; pane < 8; ++pane)
                GLDS(s2 + (size_t)pane * 8192, dst + pane * 512);
        }
        const int cb = (kt & 1) * 32768;
        bf16x8 aHf[4], aLf[4], bHf[4], bLf[4];
        #pragma unroll
        for (int f = 0; f < 4; ++f) {
            const int pA = ((wm >> 4) + f) * 1024;
            aHf[f] = *(const bf16x8*)(smem + cb + pA + lane * 16);
            aLf[f] = *(const bf16x8*)(smem + cb + 8192 + pA + lane * 16);
            const int pB = ((wn >> 4) + f) * 1024;
            bHf[f] = *(const bf16x8*)(smem + cb + 16384 + pB + lane * 16);
            bLf[f] = *(const bf16x8*)(smem + cb + 24576 + pB + lane * 16);
        }
        __builtin_amdgcn_s_setprio(1);
        #pragma unroll
        for (int mf = 0; mf < 4; ++mf)
            #pragma unroll
            for (int nf = 0; nf < 4; ++nf) {
                acc[mf][nf] = __builtin_amdgcn_mfma_f32_16x16x32_bf16(aHf[mf], bHf[nf], acc[mf][nf], 0, 0, 0);
                acc[mf][nf] = __builtin_amdgcn_mfma_f32_16x16x32_bf16(aLf[mf], bHf[nf], acc[mf][nf], 0, 0, 0);
                acc[mf][nf] = __builtin_amdgcn_mfma_f32_16x16x32_bf16(aHf[mf], bLf[nf], acc[mf][nf], 0, 0, 0);
            }
        __builtin_amdgcn_s_setprio(0);
        __syncthreads();
    }

    // ---- spill outer tile to pa as packed hi|lo bf16 (XOR-swizzled, 4-way) ----
    #pragma unroll
    for (int mf = 0; mf < 4; ++mf) {
        #pragma unroll
        for (int nf = 0; nf < 4; ++nf) {
            #pragma unroll
            for (int r = 0; r < 4; ++r) {
                int mloc = wm + mf * 16 + kgrp * 4 + r;
                int nloc = wn + nf * 16 + rl;
                int p = ((mloc >> 5) << 2) | (nloc >> 5);
                int k = ((mloc & 31) << 5) | (nloc & 31);
                float v = acc[mf][nf][r];
                unsigned short h = f2b(v);
                unsigned short l = f2b(v - b2f(h));
                pa[(p << 10) + (k ^ ((p & 3) << 3))] = (unsigned)h | ((unsigned)l << 16);
            }
        }
    }
    __syncthreads();

    // ---- epilogue GEMM: [16 pairs] x WpF^T, single pass over all 3 sections ----
    f32x4 acc2[4] = {};
    const unsigned* paRow = pa + (rl << 10);
    const int kg8 = kgrp * 8;
    #pragma unroll 4
    for (int ks = 0; ks < 32; ++ks) {
        U4B8 ua0, ua1, aHf, aLf;
        int kb = (ks * 32 + kg8) ^ ((rl & 3) << 3);
        ua0.u4 = *(const uint4*)(paRow + kb);
        ua1.u4 = *(const uint4*)(paRow + kb + 4);
        aHf.u[0] = __builtin_amdgcn_perm(ua0.u[1], ua0.u[0], 0x05040100u);
        aHf.u[1] = __builtin_amdgcn_perm(ua0.u[3], ua0.u[2], 0x05040100u);
        aHf.u[2] = __builtin_amdgcn_perm(ua1.u[1], ua1.u[0], 0x05040100u);
        aHf.u[3] = __builtin_amdgcn_perm(ua1.u[3], ua1.u[2], 0x05040100u);
        aLf.u[0] = __builtin_amdgcn_perm(ua0.u[1], ua0.u[0], 0x07060302u);
        aLf.u[1] = __builtin_amdgcn_perm(ua0.u[3], ua0.u[2], 0x07060302u);
        aLf.u[2] = __builtin_amdgcn_perm(ua1.u[1], ua1.u[0], 0x07060302u);
        aLf.u[3] = __builtin_amdgcn_perm(ua1.u[3], ua1.u[2], 0x07060302u);
        bf16x8 bHf[4], bLf[4];
        #pragma unroll
        for (int nf = 0; nf < 4; ++nf) {
            const int nb = wave * 4 + nf;
            bHf[nf] = *(const bf16x8*)&WpF[(size_t)((nb * 32 + ks) * 64 + lane) * 8];
            bLf[nf] = *(const bf16x8*)&WpF[(size_t)(((16 + nb) * 32 + ks) * 64 + lane) * 8];
        }
        __builtin_amdgcn_s_setprio(1);
        #pragma unroll
        for (int nf = 0; nf < 4; ++nf) {
            acc2[nf] = __builtin_amdgcn_mfma_f32_16x16x32_bf16(aHf.v, bHf[nf], acc2[nf], 0, 0, 0);
            acc2[nf] = __builtin_amdgcn_mfma_f32_16x16x32_bf16(aLf.v, bHf[nf], acc2[nf], 0, 0, 0);
            acc2[nf] = __builtin_amdgcn_mfma_f32_16x16x32_bf16(aHf.v, bLf[nf], acc2[nf], 0, 0, 0);
        }
        __builtin_amdgcn_s_setprio(0);
    }

    // ---- bias + SwiGLU + store ----
    const int parity = rl & 1;
    #pragma unroll
    for (int nf = 0; nf < 4; ++nf) {
        const int np = wave * 64 + nf * 16 + rl;
        const float bias = bpP[np];
        const int ocol = np >> 1;
        #pragma unroll
        for (int r = 0; r < 4; ++r) {
            float own = acc2[nf][r] + bias;
            float oth = __shfl_xor(own, 1);
            float v = parity ? oth : own;
            float g = parity ? own : oth;
            float res = v * (g / (1.0f + expf(-g)));
            if (parity == (r >> 1)) {
                int p = kgrp * 4 + r;
                int i = bx * 4 + (p >> 2);
                int j = by * 4 + (p & 3);
                out[((size_t)i * 384 + j) * 128 + ocol] = res;
            }
        }
    }
}

extern "C" void kernel_launch(void* const* d_in, const int* in_sizes, int n_in,
                              void* d_out, int out_size, void* d_ws, size_t ws_size,
                              hipStream_t stream) {
    const float* msa  = (const float*)d_in[0];
    const float* ln_g = (const float*)d_in[1];
    const float* ln_b = (const float*)d_in[2];
    const float* Wq   = (const float*)d_in[3];
    const float* Wk   = (const float*)d_in[4];
    const float* qn_g = (const float*)d_in[5];
    const float* qn_b = (const float*)d_in[6];
    const float* kn_g = (const float*)d_in[7];
    const float* kn_b = (const float*)d_in[8];
    const float* lq1  = (const float*)d_in[9];
    const float* lk1  = (const float*)d_in[10];
    const float* lq2  = (const float*)d_in[11];
    const float* lk2  = (const float*)d_in[12];
    const float* Wl   = (const float*)d_in[13];
    const float* Wr   = (const float*)d_in[14];
    const float* Wp   = (const float*)d_in[15];
    const float* bp   = (const float*)d_in[16];
    float* out = (float*)d_out;
    float* ws  = (float*)d_ws;

    float* x = ws + WS_X;
    unsigned short* AHs = (unsigned short*)(ws + WS_AEXT);
    unsigned short* ALs = (unsigned short*)(ws + WS_AEXT + 3145728u);
    unsigned short* BHs = (unsigned short*)(ws + WS_BEXT);
    unsigned short* BLs = (unsigned short*)(ws + WS_BEXT + 3145728u);
    float* qg   = ws + WS_QG;
    float* Sqg  = ws + WS_SQG;
    float* Sqb  = ws + WS_SQB;
    float* part = ws + WS_PART;
    float* wsq  = ws + WS_WSQ;
    float* bpP  = ws + WS_BPP;
    unsigned short* WpF = (unsigned short*)(ws + WS_WPF);

    prep_wp<<<256, 256, 0, stream>>>(Wp, bp, WpF, bpP);
    k1_ln<<<12288, 256, 0, stream>>>(msa, ln_g, ln_b, x);
    k2_q<<<384, 128, 0, stream>>>(x, Wq, qn_g, qn_b, kn_g, kn_b, qg, Sqg, Sqb);
    gemm_k3<<<1536, 256, 0, stream>>>(x, Wk, qg, Sqg, Sqb, part);
    k4_softmax<<<1, 512, 0, stream>>>(part, lq1, lk1, lq2, lk2, wsq);
    k5_ab<<<dim3(384, 8), 256, 0, stream>>>(x, Wl, Wr, wsq, AHs, ALs, BHs, BLs);
    gemm_fused<<<dim3(96, 96), 256, 0, stream>>>(AHs, ALs, BHs, BLs, WpF, bpP, out);
}

// Round 7
// 847.909 us; speedup vs baseline: 1.6605x; 1.0007x over previous
//
#include <hip/hip_runtime.h>
#include <hip/hip_bf16.h>
#include <math.h>

// B=1, S=512, N=384, D=64, H=32, DP=128, DQK=64
// ws layout (float offsets)
#define WS_X        0u          // x f32 [196608][64]                 = 12582912
#define WS_AEXT     12582912u   // AH frag bf16 [768*16][64][8] = 3145728 f, then AL same
#define WS_BEXT     18874368u   // BH, BL same
#define WS_QG       25165824u   // qg [2][384][64] = 49152
#define WS_SQG      25214976u   // [768]
#define WS_SQB      25215744u   // [768]
#define WS_PART     25216512u   // partial dots [2][512][3] = 3072
#define WS_WSQ      25219584u   // [512]
#define WS_BPP      25220096u   // [256]
#define WS_WPF      25220352u   // WpF bf16 frag-layout [2][16][32][64][8] = 262144 f

typedef __attribute__((ext_vector_type(8))) short bf16x8;
typedef __attribute__((ext_vector_type(4))) float f32x4;

union U4B8 { uint4 u4; unsigned u[4]; bf16x8 v; };

__device__ __forceinline__ unsigned short f2b(float x) {
    __hip_bfloat16 b = __float2bfloat16(x);
    return *reinterpret_cast<unsigned short*>(&b);
}
__device__ __forceinline__ float b2f(unsigned short u) {
    __hip_bfloat16 b = *reinterpret_cast<__hip_bfloat16*>(&u);
    return __bfloat162float(b);
}

#define GLDS(g, l) __builtin_amdgcn_global_load_lds(                                   \
    (const __attribute__((address_space(1))) unsigned int*)(g),                        \
    (__attribute__((address_space(3))) unsigned int*)(l), 16, 0, 0)

// ---------------- K1: LayerNorm over D=64, float4-vectorized (16 rows/block) ----------------
__global__ __launch_bounds__(256) void k1_ln(const float* __restrict__ msa,
                                             const float* __restrict__ g,
                                             const float* __restrict__ bb,
                                             float* __restrict__ x) {
    int row = blockIdx.x * 16 + (threadIdx.x >> 4);
    int l16 = threadIdx.x & 15;
    float4 v = ((const float4*)msa)[(size_t)row * 16 + l16];
    float sum = v.x + v.y + v.z + v.w;
    #pragma unroll
    for (int m = 1; m < 16; m <<= 1) sum += __shfl_xor(sum, m);
    float mean = sum * (1.0f / 64.0f);
    float4 dv = make_float4(v.x - mean, v.y - mean, v.z - mean, v.w - mean);
    float sq = dv.x * dv.x + dv.y * dv.y + dv.z * dv.z + dv.w * dv.w;
    #pragma unroll
    for (int m = 1; m < 16; m <<= 1) sq += __shfl_xor(sq, m);
    float r = rsqrtf(sq * (1.0f / 64.0f) + 1e-5f);
    float4 g4 = ((const float4*)g)[l16];
    float4 b4 = ((const float4*)bb)[l16];
    ((float4*)x)[(size_t)row * 16 + l16] = make_float4(
        dv.x * r * g4.x + b4.x, dv.y * r * g4.y + b4.y,
        dv.z * r * g4.z + b4.z, dv.w * r * g4.w + b4.w);
}

// ---------------- K2: q projection + LN, emit qg = qn*kn_g, Sqg, Sqb ----------------
__global__ __launch_bounds__(128) void k2_q(const float* __restrict__ x,
                                            const float* __restrict__ Wq,
                                            const float* __restrict__ qg_,
                                            const float* __restrict__ qb_,
                                            const float* __restrict__ kg_,
                                            const float* __restrict__ kb_,
                                            float* __restrict__ qgOut,
                                            float* __restrict__ SqgOut,
                                            float* __restrict__ SqbOut) {
    int n = blockIdx.x;
    int tt = threadIdx.x >> 6;
    int d = threadIdx.x & 63;
    const float* xr = x + (size_t)n * 64;
    const float* w  = Wq + (size_t)(tt * 64 + d) * 64;
    float acc = 0.f;
    #pragma unroll 8
    for (int dd = 0; dd < 64; ++dd) acc += xr[dd] * w[dd];
    float sum = acc;
    #pragma unroll
    for (int m = 1; m < 64; m <<= 1) sum += __shfl_xor(sum, m);
    float mean = sum * (1.0f / 64.0f);
    float dv = acc - mean;
    float sq = dv * dv;
    #pragma unroll
    for (int m = 1; m < 64; m <<= 1) sq += __shfl_xor(sq, m);
    float r = rsqrtf(sq * (1.0f / 64.0f) + 1e-5f);
    float qnv = dv * r * qg_[d] + qb_[d];
    float qgv = qnv * kg_[d];
    float sb  = qnv * kb_[d];
    float sg  = qgv;
    #pragma unroll
    for (int m = 1; m < 64; m <<= 1) { sg += __shfl_xor(sg, m); sb += __shfl_xor(sb, m); }
    qgOut[(size_t)(tt * 384 + n) * 64 + d] = qgv;
    if (d == 0) { SqgOut[tt * 384 + n] = sg; SqbOut[tt * 384 + n] = sb; }
}

// ---------------- gemm_k3: kraw tile (fp32 GEMM) + LN-dot epilogue -> partials ----------------
__global__ __launch_bounds__(256) void gemm_k3(const float* __restrict__ X,
                                               const float* __restrict__ Wk,
                                               const float* __restrict__ qg,
                                               const float* __restrict__ Sqg,
                                               const float* __restrict__ Sqb,
                                               float* __restrict__ part) {
    __shared__ __align__(16) char smem[65536];
    float (*AsT)[132] = (float(*)[132])smem;
    float (*BsT)[132] = (float(*)[132])(smem + 16896);
    float* kbuf = (float*)smem;   // aliases AsT/BsT after GEMM completes

    int t  = threadIdx.x;
    int m0 = blockIdx.x * 128;
    int s  = m0 / 384;
    int nchunk = (m0 - s * 384) >> 7;
    int tr = t >> 4, tc = t & 15;
    float acc[8][8] = {};
    int rrow = t >> 3;
    int kk   = (t & 7) * 4;
    for (int k0 = 0; k0 < 64; k0 += 32) {
        #pragma unroll
        for (int l = 0; l < 4; ++l) {
            int row = rrow + 32 * l;
            float4 va = *(const float4*)(X + (size_t)(m0 + row) * 64 + k0 + kk);
            AsT[kk + 0][row] = va.x; AsT[kk + 1][row] = va.y;
            AsT[kk + 2][row] = va.z; AsT[kk + 3][row] = va.w;
            float4 vb = *(const float4*)(Wk + (size_t)row * 64 + k0 + kk);
            BsT[kk + 0][row] = vb.x; BsT[kk + 1][row] = vb.y;
            BsT[kk + 2][row] = vb.z; BsT[kk + 3][row] = vb.w;
        }
        __syncthreads();
        #pragma unroll 4
        for (int k = 0; k < 32; ++k) {
            float a[8], b[8];
            *(float4*)&a[0] = *(const float4*)&AsT[k][tr * 8];
            *(float4*)&a[4] = *(const float4*)&AsT[k][tr * 8 + 4];
            *(float4*)&b[0] = *(const float4*)&BsT[k][tc * 8];
            *(float4*)&b[4] = *(const float4*)&BsT[k][tc * 8 + 4];
            #pragma unroll
            for (int q = 0; q < 8; ++q)
                #pragma unroll
                for (int j = 0; j < 8; ++j)
                    acc[q][j] += a[q] * b[j];
        }
        __syncthreads();
    }
    #pragma unroll
    for (int q = 0; q < 8; ++q) {
        int m = tr * 8 + q;
        int swz = (m & 15) << 4;
        int b0 = m * 512 + (((tc * 2) * 16) ^ swz);
        int b1 = m * 512 + (((tc * 2 + 1) * 16) ^ swz);
        *(float4*)((char*)kbuf + b0) = make_float4(acc[q][0], acc[q][1], acc[q][2], acc[q][3]);
        *(float4*)((char*)kbuf + b1) = make_float4(acc[q][4], acc[q][5], acc[q][6], acc[q][7]);
    }
    __syncthreads();
    int r  = t & 127;
    int tt = t >> 7;
    int n  = nchunk * 128 + r;
    const char* base = (const char*)kbuf + r * 512;
    const float4* qgp = (const float4*)(qg + ((size_t)(tt * 384 + n)) * 64);
    int swz = (r & 15) << 4;
    float s1 = 0.f, s2 = 0.f, s3 = 0.f;
    #pragma unroll
    for (int i = 0; i < 16; ++i) {
        float4 kv = *(const float4*)(base + ((((tt * 16 + i) * 16) ^ swz)));
        float4 qv = qgp[i];
        s1 += kv.x + kv.y + kv.z + kv.w;
        s2 += kv.x * kv.x + kv.y * kv.y + kv.z * kv.z + kv.w * kv.w;
        s3 += kv.x * qv.x + kv.y * qv.y + kv.z * qv.z + kv.w * qv.w;
    }
    float mu  = s1 * (1.0f / 64.0f);
    float var = s2 * (1.0f / 64.0f) - mu * mu;
    float rln = rsqrtf(var + 1e-5f);
    float dot = rln * (s3 - mu * Sqg[tt * 384 + n]) + Sqb[tt * 384 + n];
    #pragma unroll
    for (int m = 1; m < 64; m <<= 1) dot += __shfl_xor(dot, m);
    __syncthreads();
    if ((t & 63) == 0) kbuf[t >> 6] = dot;
    __syncthreads();
    if (t == 0) part[((size_t)0 * 512 + s) * 3 + nchunk] = kbuf[0] + kbuf[1];
    if (t == 1) part[((size_t)1 * 512 + s) * 3 + nchunk] = kbuf[2] + kbuf[3];
}

// ---------------- K4: lambda, softmax over s, sqrt weights (reads partials) ----------------
__global__ __launch_bounds__(512) void k4_softmax(const float* __restrict__ part,
                                                  const float* __restrict__ lq1,
                                                  const float* __restrict__ lk1,
                                                  const float* __restrict__ lq2,
                                                  const float* __restrict__ lk2,
                                                  float* __restrict__ wsq) {
    int s = threadIdx.x;
    float l1 = 0.f, l2 = 0.f;
    for (int i = 0; i < 64; ++i) { l1 += lq1[i] * lk1[i]; l2 += lq2[i] * lk2[i]; }
    float lam = expf(l1) - expf(l2) + 1.0f;
    const float c = 0.125f / 384.0f;
    float a0 = (part[s * 3] + part[s * 3 + 1] + part[s * 3 + 2]) * c;
    float a1 = (part[(512 + s) * 3] + part[(512 + s) * 3 + 1] + part[(512 + s) * 3 + 2]) * c;
    float v = a0 - lam * a1;
    __shared__ float red[512];
    red[s] = v;
    __syncthreads();
    for (int off = 256; off > 0; off >>= 1) {
        if (s < off) red[s] = fmaxf(red[s], red[s + off]);
        __syncthreads();
    }
    float mx = red[0];
    __syncthreads();
    float e = expf(v - mx);
    red[s] = e;
    __syncthreads();
    for (int off = 256; off > 0; off >>= 1) {
        if (s < off) red[s] += red[s + off];
        __syncthreads();
    }
    wsq[s] = sqrtf(e / red[0] + 1e-32f);
}

// ---------------- K5: build A/B hi-lo splits in MFMA-frag-native layout ----------------
__global__ __launch_bounds__(256) void k5_ab(const float* __restrict__ x,
                                             const float* __restrict__ Wl,
                                             const float* __restrict__ Wr,
                                             const float* __restrict__ wsq,
                                             unsigned short* __restrict__ AHo,
                                             unsigned short* __restrict__ ALo,
                                             unsigned short* __restrict__ BHo,
                                             unsigned short* __restrict__ BLo) {
    int i  = blockIdx.x;
    int s0 = blockIdx.y * 64;
    int t  = threadIdx.x;
    __shared__ __align__(16) float wl[2048], wr[2048];
    __shared__ float xT[64][69];
    ((float4*)wl)[t * 2]     = ((const float4*)Wl)[t * 2];
    ((float4*)wl)[t * 2 + 1] = ((const float4*)Wl)[t * 2 + 1];
    ((float4*)wr)[t * 2]     = ((const float4*)Wr)[t * 2];
    ((float4*)wr)[t * 2 + 1] = ((const float4*)Wr)[t * 2 + 1];
    {
        int s_l = t >> 2, d0 = (t & 3) * 16;
        const float* xr = x + ((size_t)(s0 + s_l) * 384 + i) * 64 + d0;
        #pragma unroll
        for (int j = 0; j < 4; ++j) {
            float4 v = *(const float4*)(xr + j * 4);
            xT[d0 + j * 4 + 0][s_l] = v.x; xT[d0 + j * 4 + 1][s_l] = v.y;
            xT[d0 + j * 4 + 2][s_l] = v.z; xT[d0 + j * 4 + 3][s_l] = v.w;
        }
    }
    __syncthreads();
    int c = t >> 3, so = (t & 7) * 8;
    float aa[8] = {}, bb2[8] = {};
    #pragma unroll 8
    for (int d = 0; d < 64; ++d) {
        float wlv = wl[c * 64 + d], wrv = wr[c * 64 + d];
        #pragma unroll
        for (int q = 0; q < 8; ++q) {
            float xv = xT[d][so + q];
            aa[q]  += xv * wlv;
            bb2[q] += xv * wrv;
        }
    }
    #pragma unroll
    for (int q = 0; q < 8; ++q) {
        float wq = wsq[s0 + so + q];
        aa[q] *= wq; bb2[q] *= wq;
    }
    int m = i * 32 + c;
    int s = s0 + so;
    size_t idx = (((size_t)(m >> 4) * 16 + (s >> 5)) * 64 + ((m & 15) | (((s >> 3) & 3) << 4))) * 8;
    {
        unsigned short h[8], l[8];
        #pragma unroll
        for (int q = 0; q < 8; ++q) { h[q] = f2b(aa[q]); l[q] = f2b(aa[q] - b2f(h[q])); }
        *(uint4*)&AHo[idx] = make_uint4((unsigned)h[0] | ((unsigned)h[1] << 16), (unsigned)h[2] | ((unsigned)h[3] << 16),
                                        (unsigned)h[4] | ((unsigned)h[5] << 16), (unsigned)h[6] | ((unsigned)h[7] << 16));
        *(uint4*)&ALo[idx] = make_uint4((unsigned)l[0] | ((unsigned)l[1] << 16), (unsigned)l[2] | ((unsigned)l[3] << 16),
                                        (unsigned)l[4] | ((unsigned)l[5] << 16), (unsigned)l[6] | ((unsigned)l[7] << 16));
    }
    {
        unsigned short h[8], l[8];
        #pragma unroll
        for (int q = 0; q < 8; ++q) { h[q] = f2b(bb2[q]); l[q] = f2b(bb2[q] - b2f(h[q])); }
        *(uint4*)&BHo[idx] = make_uint4((unsigned)h[0] | ((unsigned)h[1] << 16), (unsigned)h[2] | ((unsigned)h[3] << 16),
                                        (unsigned)h[4] | ((unsigned)h[5] << 16), (unsigned)h[6] | ((unsigned)h[7] << 16));
        *(uint4*)&BLo[idx] = make_uint4((unsigned)l[0] | ((unsigned)l[1] << 16), (unsigned)l[2] | ((unsigned)l[3] << 16),
                                        (unsigned)l[4] | ((unsigned)l[5] << 16), (unsigned)l[6] | ((unsigned)l[7] << 16));
    }
}

// ---------------- prep: WpF frag layout [bsel][nb][kstep][lane][8] + bpP ----------------
__global__ __launch_bounds__(256) void prep_wp(const float* __restrict__ Wp,
                                               const float* __restrict__ bp,
                                               unsigned short* __restrict__ WpF,
                                               float* __restrict__ bpP) {
    int gid = blockIdx.x * 256 + threadIdx.x;
    int lane  = gid & 63;
    int kstep = (gid >> 6) & 31;
    int nb    = (gid >> 11) & 15;
    int bsel  = gid >> 15;
    int rl = lane & 15, kg = lane >> 4;
    int urow = nb * 16 + rl;
    int srow = (urow & 1) ? 128 + (urow >> 1) : (urow >> 1);
    int k0 = kstep * 32 + kg * 8;
    const float* src = Wp + (size_t)srow * 1024 + k0;
    unsigned short o[8];
    #pragma unroll
    for (int e = 0; e < 8; ++e) {
        float w = src[e];
        unsigned short h = f2b(w);
        o[e] = bsel ? f2b(w - b2f(h)) : h;
    }
    *(uint4*)&WpF[(size_t)gid * 8] = make_uint4(
        (unsigned)o[0] | ((unsigned)o[1] << 16), (unsigned)o[2] | ((unsigned)o[3] << 16),
        (unsigned)o[4] | ((unsigned)o[5] << 16), (unsigned)o[6] | ((unsigned)o[7] << 16));
    if (blockIdx.x == 0) {
        int tt = threadIdx.x;
        bpP[tt] = bp[(tt & 1) ? 128 + (tt >> 1) : (tt >> 1)];
    }
}

// ---------------- FUSED: outer tile (counted-vmcnt dbuf, bf16x3) + Wp proj + SwiGLU ----------------
__global__ __launch_bounds__(256) void gemm_fused(const unsigned short* __restrict__ AH,
                                                  const unsigned short* __restrict__ AL,
                                                  const unsigned short* __restrict__ BHm,
                                                  const unsigned short* __restrict__ BLm,
                                                  const unsigned short* __restrict__ WpF,
                                                  const float* __restrict__ bpP,
                                                  float* __restrict__ out) {
    __shared__ __align__(16) unsigned char smem[65536];
    unsigned* pa = (unsigned*)smem;                       // [16][1024] packed hi|lo u32

    const int t = threadIdx.x;
    const int wave = t >> 6, lane = t & 63;
    const int bx = blockIdx.x, by = blockIdx.y;
    const int m0 = bx * 128, n0 = by * 128;
    const int wm = (wave & 1) * 64, wn = (wave >> 1) * 64;
    const int kgrp = lane >> 4, rl = lane & 15;
    f32x4 acc[4][4] = {};

    const unsigned short* srcArr = (wave == 0) ? AH : (wave == 1) ? AL : (wave == 2) ? BHm : BLm;
    const unsigned short* srcBase = srcArr + ((size_t)(((wave < 2) ? m0 : n0) >> 4) * 16) * 512 + lane * 8;
    unsigned short* dstW = (unsigned short*)smem + wave * 4096;

    // prologue: stage kt=0 into buf0 (8 GLDS in flight)
    #pragma unroll
    for (int pane = 0; pane < 8; ++pane)
        GLDS(srcBase + (size_t)pane * 8192, dstW + pane * 512);

    #pragma unroll 2
    for (int kt = 0; kt < 16; ++kt) {
        if (kt < 15) {
            // issue next stage (8 GLDS) into the other buffer; its reads happened 2 barriers ago
            unsigned short* dst = dstW + ((kt + 1) & 1) * 16384;
            const unsigned short* s2 = srcBase + (size_t)(kt + 1) * 512;
            #pragma unroll
            for (int pane = 0; pane < 8; ++pane)
                GLDS(s2 + (size_t)pane * 8192, dst + pane * 512);
            // wait only for stage(kt)'s 8 loads: the 8 just issued stay in flight
            asm volatile("s_waitcnt vmcnt(8)" ::: "memory");
        } else {
            asm volatile("s_waitcnt vmcnt(0)" ::: "memory");
        }
        __builtin_amdgcn_s_barrier();          // all waves landed stage(kt) -> buf[kt&1] readable
        asm volatile("" ::: "memory");
        const int cb = (kt & 1) * 32768;
        bf16x8 aHf[4], aLf[4], bHf[4], bLf[4];
        #pragma unroll
        for (int f = 0; f < 4; ++f) {
            const int pA = ((wm >> 4) + f) * 1024;
            aHf[f] = *(const bf16x8*)(smem + cb + pA + lane * 16);
            aLf[f] = *(const bf16x8*)(smem + cb + 8192 + pA + lane * 16);
            const int pB = ((wn >> 4) + f) * 1024;
            bHf[f] = *(const bf16x8*)(smem + cb + 16384 + pB + lane * 16);
            bLf[f] = *(const bf16x8*)(smem + cb + 24576 + pB + lane * 16);
        }
        __builtin_amdgcn_s_setprio(1);
        #pragma unroll
        for (int mf = 0; mf < 4; ++mf)
            #pragma unroll
            for (int nf = 0; nf < 4; ++nf) {
                acc[mf][nf] = __builtin_amdgcn_mfma_f32_16x16x32_bf16(aHf[mf], bHf[nf], acc[mf][nf], 0, 0, 0);
                acc[mf][nf] = __builtin_amdgcn_mfma_f32_16x16x32_bf16(aLf[mf], bHf[nf], acc[mf][nf], 0, 0, 0);
                acc[mf][nf] = __builtin_amdgcn_mfma_f32_16x16x32_bf16(aHf[mf], bLf[nf], acc[mf][nf], 0, 0, 0);
            }
        __builtin_amdgcn_s_setprio(0);
        asm volatile("" ::: "memory");
        __builtin_amdgcn_s_barrier();          // all waves done reading buf[kt&1] (reads consumed by MFMAs)
        asm volatile("" ::: "memory");
    }

    // ---- spill outer tile to pa as packed hi|lo bf16 (XOR-swizzled, 4-way) ----
    #pragma unroll
    for (int mf = 0; mf < 4; ++mf) {
        #pragma unroll
        for (int nf = 0; nf < 4; ++nf) {
            #pragma unroll
            for (int r = 0; r < 4; ++r) {
                int mloc = wm + mf * 16 + kgrp * 4 + r;
                int nloc = wn + nf * 16 + rl;
                int p = ((mloc >> 5) << 2) | (nloc >> 5);
                int k = ((mloc & 31) << 5) | (nloc & 31);
                float v = acc[mf][nf][r];
                unsigned short h = f2b(v);
                unsigned short l = f2b(v - b2f(h));
                pa[(p << 10) + (k ^ ((p & 3) << 3))] = (unsigned)h | ((unsigned)l << 16);
            }
        }
    }
    __syncthreads();

    // ---- epilogue GEMM: [16 pairs] x WpF^T, single pass over all 3 sections ----
    f32x4 acc2[4] = {};
    const unsigned* paRow = pa + (rl << 10);
    const int kg8 = kgrp * 8;
    #pragma unroll 4
    for (int ks = 0; ks < 32; ++ks) {
        U4B8 ua0, ua1, aHf, aLf;
        int kb = (ks * 32 + kg8) ^ ((rl & 3) << 3);
        ua0.u4 = *(const uint4*)(paRow + kb);
        ua1.u4 = *(const uint4*)(paRow + kb + 4);
        aHf.u[0] = __builtin_amdgcn_perm(ua0.u[1], ua0.u[0], 0x05040100u);
        aHf.u[1] = __builtin_amdgcn_perm(ua0.u[3], ua0.u[2], 0x05040100u);
        aHf.u[2] = __builtin_amdgcn_perm(ua1.u[1], ua1.u[0], 0x05040100u);
        aHf.u[3] = __builtin_amdgcn_perm(ua1.u[3], ua1.u[2], 0x05040100u);
        aLf.u[0] = __builtin_amdgcn_perm(ua0.u[1], ua0.u[0], 0x07060302u);
        aLf.u[1] = __builtin_amdgcn_perm(ua0.u[3], ua0.u[2], 0x07060302u);
        aLf.u[2] = __builtin_amdgcn_perm(ua1.u[1], ua1.u[0], 0x07060302u);
        aLf.u[3] = __builtin_amdgcn_perm(ua1.u[3], ua1.u[2], 0x07060302u);
        bf16x8 bHf[4], bLf[4];
        #pragma unroll
        for (int nf = 0; nf < 4; ++nf) {
            const int nb = wave * 4 + nf;
            bHf[nf] = *(const bf16x8*)&WpF[(size_t)((nb * 32 + ks) * 64 + lane) * 8];
            bLf[nf] = *(const bf16x8*)&WpF[(size_t)(((16 + nb) * 32 + ks) * 64 + lane) * 8];
        }
        __builtin_amdgcn_s_setprio(1);
        #pragma unroll
        for (int nf = 0; nf < 4; ++nf) {
            acc2[nf] = __builtin_amdgcn_mfma_f32_16x16x32_bf16(aHf.v, bHf[nf], acc2[nf], 0, 0, 0);
            acc2[nf] = __builtin_amdgcn_mfma_f32_16x16x32_bf16(aLf.v, bHf[nf], acc2[nf], 0, 0, 0);
            acc2[nf] = __builtin_amdgcn_mfma_f32_16x16x32_bf16(aHf.v, bLf[nf], acc2[nf], 0, 0, 0);
        }
        __builtin_amdgcn_s_setprio(0);
    }

    // ---- bias + SwiGLU + store ----
    const int parity = rl & 1;
    #pragma unroll
    for (int nf = 0; nf < 4; ++nf) {
        const int np = wave * 64 + nf * 16 + rl;
        const float bias = bpP[np];
        const int ocol = np >> 1;
        #pragma unroll
        for (int r = 0; r < 4; ++r) {
            float own = acc2[nf][r] + bias;
            float oth = __shfl_xor(own, 1);
            float v = parity ? oth : own;
            float g = parity ? own : oth;
            float res = v * (g / (1.0f + expf(-g)));
            if (parity == (r >> 1)) {
                int p = kgrp * 4 + r;
                int i = bx * 4 + (p >> 2);
                int j = by * 4 + (p & 3);
                out[((size_t)i * 384 + j) * 128 + ocol] = res;
            }
        }
    }
}

extern "C" void kernel_launch(void* const* d_in, const int* in_sizes, int n_in,
                              void* d_out, int out_size, void* d_ws, size_t ws_size,
                              hipStream_t stream) {
    const float* msa  = (const float*)d_in[0];
    const float* ln_g = (const float*)d_in[1];
    const float* ln_b = (const float*)d_in[2];
    const float* Wq   = (const float*)d_in[3];
    const float* Wk   = (const float*)d_in[4];
    const float* qn_g = (const float*)d_in[5];
    const float* qn_b = (const float*)d_in[6];
    const float* kn_g = (const float*)d_in[7];
    const float* kn_b = (const float*)d_in[8];
    const float* lq1  = (const float*)d_in[9];
    const float* lk1  = (const float*)d_in[10];
    const float* lq2  = (const float*)d_in[11];
    const float* lk2  = (const float*)d_in[12];
    const float* Wl   = (const float*)d_in[13];
    const float* Wr   = (const float*)d_in[14];
    const float* Wp   = (const float*)d_in[15];
    const float* bp   = (const float*)d_in[16];
    float* out = (float*)d_out;
    float* ws  = (float*)d_ws;

    float* x = ws + WS_X;
    unsigned short* AHs = (unsigned short*)(ws + WS_AEXT);
    unsigned short* ALs = (unsigned short*)(ws + WS_AEXT + 3145728u);
    unsigned short* BHs = (unsigned short*)(ws + WS_BEXT);
    unsigned short* BLs = (unsigned short*)(ws + WS_BEXT + 3145728u);
    float* qg   = ws + WS_QG;
    float* Sqg  = ws + WS_SQG;
    float* Sqb  = ws + WS_SQB;
    float* part = ws + WS_PART;
    float* wsq  = ws + WS_WSQ;
    float* bpP  = ws + WS_BPP;
    unsigned short* WpF = (unsigned short*)(ws + WS_WPF);

    prep_wp<<<256, 256, 0, stream>>>(Wp, bp, WpF, bpP);
    k1_ln<<<12288, 256, 0, stream>>>(msa, ln_g, ln_b, x);
    k2_q<<<384, 128, 0, stream>>>(x, Wq, qn_g, qn_b, kn_g, kn_b, qg, Sqg, Sqb);
    gemm_k3<<<1536, 256, 0, stream>>>(x, Wk, qg, Sqg, Sqb, part);
    k4_softmax<<<1, 512, 0, stream>>>(part, lq1, lk1, lq2, lk2, wsq);
    k5_ab<<<dim3(384, 8), 256, 0, stream>>>(x, Wl, Wr, wsq, AHs, ALs, BHs, BLs);
    gemm_fused<<<dim3(96, 96), 256, 0, stream>>>(AHs, ALs, BHs, BLs, WpF, bpP, out);
}